// Round 1
// baseline (433.468 us; speedup 1.0000x reference)
//
#include <hip/hip_runtime.h>
#include <math.h>

// S4 liquid forward. Shapes: B=4, H=256, L=4096, N2=32 half-modes, C=1.
// Strategy: chunked state-space scan (rank-32 kernel) instead of FFT conv.
//   K1 setup : per (h,n) mode tables in double: P[p]=dB*dA^p, E[t]=2*C*dA^(t+1),
//              kshort[d]=2Re(sum C dB dA^d), dA^T, dCB (liquid scalar).
//   K2 local : per-chunk local state sums Lsum[b,h,c,n] = sum_j dA^{T-1-j} dB u.
//   K3 scan  : S[c] = dA^T S[c-1] + Lsum[c-1]  (in-place, 64 steps).
//   K4 main  : y[l] = Re(E[t]·S_c) + intra Toeplitz conv + D*u + dCB*u*u_prev,
//              then gelu(tanh approx) -> YG.
//   K5 out   : out[b,o,l] = sum_h W[o,h]*YG[b,h,l] + bias[o]  (fp32 reg-tiled).

#define H 256
#define LSEQ 4096
#define NB 4
#define NMODES 32
#define T 64
#define NC 64   // LSEQ / T

__global__ __launch_bounds__(64) void k_setup(
    const float* __restrict__ log_dt, const float* __restrict__ w_re, const float* __restrict__ w_im,
    const float* __restrict__ B_re, const float* __restrict__ B_im,
    const float* __restrict__ C_re, const float* __restrict__ C_im,
    float2* __restrict__ P, float2* __restrict__ E, float* __restrict__ kshort,
    float2* __restrict__ dAT, float* __restrict__ dCB)
{
    int lane = threadIdx.x;
    int h = blockIdx.x * 2 + (lane >> 5);
    int n = lane & 31;
    int hn = h * NMODES + n;

    double dt = exp((double)log_dt[h]);
    double zr = 0.5 * dt * (double)w_re[hn], zi = 0.5 * dt * (double)w_im[hn];
    double dr = 1.0 - zr, di = -zi;
    double dn = dr * dr + di * di;
    double nr = 1.0 + zr, ni = zi;
    double dAr = (nr * dr + ni * di) / dn, dAi = (ni * dr - nr * di) / dn;
    double tbr = dt * (double)B_re[hn], tbi = dt * (double)B_im[hn];
    double dBr = (tbr * dr + tbi * di) / dn, dBi = (tbi * dr - tbr * di) / dn;
    double Cr = (double)C_re[hn], Ci = (double)C_im[hn];
    double CBr = Cr * dBr - Ci * dBi, CBi = Cr * dBi + Ci * dBr;

    double ar = 1.0, ai = 0.0;  // dA^p
    for (int p = 0; p < T; ++p) {
        // P[h][p][n] = dB * dA^p
        double pr = dBr * ar - dBi * ai, pi = dBr * ai + dBi * ar;
        P[(h * T + p) * NMODES + n] = make_float2((float)pr, (float)pi);
        // kshort[h][p] = 2 * Re(sum_n C*dB*dA^p)
        double q = CBr * ar - CBi * ai;
        #pragma unroll
        for (int m = 16; m >= 1; m >>= 1) q += __shfl_xor(q, m);
        if (n == 0) kshort[h * T + p] = (float)(2.0 * q);
        // a *= dA  -> dA^{p+1}
        double nar = ar * dAr - ai * dAi;
        ai = ar * dAi + ai * dAr; ar = nar;
        // E[h][n][p] = 2*C*dA^{p+1}   (t-major inner for coalesced reads in K4)
        double er = 2.0 * (Cr * ar - Ci * ai), ei = 2.0 * (Cr * ai + Ci * ar);
        E[(h * NMODES + n) * T + p] = make_float2((float)er, (float)ei);
    }
    dAT[hn] = make_float2((float)ar, (float)ai);  // dA^T
    // liquid scalar: dCB[h] = (2*Re sum dB) * (2*Re sum C*dB)
    double s1 = dBr, s2 = CBr;
    #pragma unroll
    for (int m = 16; m >= 1; m >>= 1) { s1 += __shfl_xor(s1, m); s2 += __shfl_xor(s2, m); }
    if (n == 0) dCB[h] = (float)(4.0 * s1 * s2);
}

// Lsum[b,h,c,n] = sum_{j=0}^{T-1} P[h][T-1-j][n] * u[b,h,c*T+j]
__global__ __launch_bounds__(256) void k_local(
    const float* __restrict__ u, const float2* __restrict__ P, float2* __restrict__ SL)
{
    int tid = threadIdx.x;
    int n = tid & 31, csub = tid >> 5;           // 8 chunks per block
    int bh = blockIdx.x >> 3;                    // b*H + h
    int c = ((blockIdx.x & 7) << 3) + csub;
    int h = bh & (H - 1);
    const float* ub = u + bh * LSEQ + c * T;
    const float2* Ph = P + h * T * NMODES + n;
    float2 acc = make_float2(0.f, 0.f);
    #pragma unroll 8
    for (int j = 0; j < T; ++j) {
        float uv = ub[j];
        float2 p = Ph[(T - 1 - j) * NMODES];
        acc.x += p.x * uv; acc.y += p.y * uv;
    }
    SL[(bh * NC + c) * NMODES + n] = acc;
}

// in-place scan: slot c gets state entering chunk c (= x[c*T-1]); S_0 = 0
__global__ __launch_bounds__(256) void k_scan(
    const float2* __restrict__ dAT, float2* __restrict__ SL)
{
    int gid = blockIdx.x * 256 + threadIdx.x;    // (b*H+h)*32 + n
    int n = gid & 31;
    int bh = gid >> 5;
    int h = bh & (H - 1);
    float2 A = dAT[h * NMODES + n];
    float2 S = make_float2(0.f, 0.f);
    float2* base = SL + (size_t)bh * NC * NMODES + n;
    for (int c = 0; c < NC; ++c) {
        float2 tmp = base[c * NMODES];
        base[c * NMODES] = S;
        float sr = S.x * A.x - S.y * A.y + tmp.x;
        float si = S.x * A.y + S.y * A.x + tmp.y;
        S = make_float2(sr, si);
    }
}

__global__ __launch_bounds__(256) void k_main(
    const float* __restrict__ u, const float2* __restrict__ E,
    const float* __restrict__ kshort, const float2* __restrict__ SL,
    const float* __restrict__ dCB, const float* __restrict__ D,
    float* __restrict__ YG)
{
    __shared__ float u_s[4][66];
    int tid = threadIdx.x;
    int t = tid & 63, csub = tid >> 6;           // one chunk per wave
    int bh = blockIdx.x >> 4;                    // 4 chunks per block
    int c = ((blockIdx.x & 15) << 2) + csub;
    int h = bh & (H - 1);
    int l0 = c * T;
    const float* ub = u + bh * LSEQ;

    u_s[csub][t + 1] = ub[l0 + t];
    if (t == 0) u_s[csub][0] = (l0 == 0) ? 0.f : ub[l0 - 1];
    __syncthreads();

    // boundary: Re( sum_n E[h][n][t] * S[b,h,c,n] )
    float bacc = 0.f;
    const float2* Eh = E + (size_t)(h * NMODES) * T + t;
    const float2* Sc = SL + (size_t)(bh * NC + c) * NMODES;
    #pragma unroll 8
    for (int n = 0; n < NMODES; ++n) {
        float2 e = Eh[n * T];
        float2 s = Sc[n];
        bacc += e.x * s.x - e.y * s.y;
    }
    // intra-chunk Toeplitz: sum_{d=0}^{t} kshort[h][d] * u[l-d]
    float iacc = 0.f;
    const float* ks = kshort + h * T;
    const float* uc = &u_s[csub][1];
    for (int d = 0; d <= t; ++d) iacc += ks[d] * uc[t - d];

    float uv = uc[t];
    float up = u_s[csub][t];   // u[l-1] (0 at l==0)
    float y = bacc + iacc + D[h] * uv + dCB[h] * uv * up;
    // gelu, tanh approximation (JAX default approximate=True)
    float y3 = y * y * y;
    float g = 0.5f * y * (1.f + tanhf(0.7978845608028654f * (y + 0.044715f * y3)));
    YG[(size_t)bh * LSEQ + l0 + t] = g;
}

// out[b,o,l] = sum_h W[o,h] * YG[b,h,l] + bias[o]
__global__ __launch_bounds__(256) void k_out(
    const float* __restrict__ YG, const float* __restrict__ W,
    const float* __restrict__ bias, float* __restrict__ out)
{
    int tid = threadIdx.x;
    int ltile = blockIdx.x;                      // 16
    int og = blockIdx.y;                         // 8 groups of 32 outputs
    int b = blockIdx.z;                          // 4
    int l = ltile * 256 + tid;

    float acc[32];
    #pragma unroll
    for (int o = 0; o < 32; ++o) acc[o] = 0.f;

    for (int hs = 0; hs < 8; ++hs) {
        float v[32];
        #pragma unroll
        for (int hh = 0; hh < 32; ++hh)
            v[hh] = YG[(size_t)(b * H + hs * 32 + hh) * LSEQ + l];  // coalesced
        #pragma unroll
        for (int o = 0; o < 32; ++o) {
            const float* Wrow = W + (size_t)(og * 32 + o) * H + hs * 32;
            float a = acc[o];
            #pragma unroll
            for (int hh = 0; hh < 32; ++hh) a += Wrow[hh] * v[hh];
            acc[o] = a;
        }
    }
    #pragma unroll
    for (int o = 0; o < 32; ++o)
        out[(size_t)(b * H + og * 32 + o) * LSEQ + l] = acc[o] + bias[og * 32 + o];
}

extern "C" void kernel_launch(void* const* d_in, const int* in_sizes, int n_in,
                              void* d_out, int out_size, void* d_ws, size_t ws_size,
                              hipStream_t stream) {
    const float* u      = (const float*)d_in[0];
    const float* log_dt = (const float*)d_in[1];
    const float* w_re   = (const float*)d_in[2];
    const float* w_im   = (const float*)d_in[3];
    const float* B_re   = (const float*)d_in[4];
    const float* B_im   = (const float*)d_in[5];
    const float* C_re   = (const float*)d_in[6];
    const float* C_im   = (const float*)d_in[7];
    const float* Dp     = (const float*)d_in[8];
    const float* Wp     = (const float*)d_in[9];
    const float* bias   = (const float*)d_in[10];
    float* out = (float*)d_out;
    float* ws = (float*)d_ws;

    // workspace layout (float offsets, all float2 regions 8B-aligned)
    float2* P      = (float2*)(ws);                    // H*T*NMODES cplx   = 2,097,152 f
    float2* E      = (float2*)(ws + 1048576 * 2);      // wait-free: see below
    // NOTE: P occupies 2*H*T*NMODES = 1,048,576 floats
    E              = (float2*)(ws + 1048576);          // another 1,048,576 f
    float* kshort  = ws + 2097152;                     // 16,384 f
    float2* dAT    = (float2*)(ws + 2113536);          // 16,384 f
    float* dCB     = ws + 2129920;                     // 256 f
    float2* SL     = (float2*)(ws + 2130176);          // B*H*NC*NMODES cplx = 4,194,304 f
    float* YG      = ws + 2130176 + 4194304;           // 4,194,304 f
    // total = 10,518,784 floats = 42.1 MB

    k_setup<<<H / 2, 64, 0, stream>>>(log_dt, w_re, w_im, B_re, B_im, C_re, C_im,
                                      P, E, kshort, dAT, dCB);
    k_local<<<NB * H * 8, 256, 0, stream>>>(u, P, SL);
    k_scan<<<NB * H * NMODES / 256, 256, 0, stream>>>(dAT, SL);
    k_main<<<NB * H * 16, 256, 0, stream>>>(u, E, kshort, SL, dCB, Dp, YG);
    dim3 g5(LSEQ / 256, 8, NB);
    k_out<<<g5, 256, 0, stream>>>(YG, Wp, bias, out);
}

// Round 2
// 319.467 us; speedup vs baseline: 1.3568x; 1.3568x over previous
//
#include <hip/hip_runtime.h>
#include <math.h>

// S4 liquid forward. Shapes: B=4, H=256, L=4096, N2=32 half-modes, C=1.
// Chunked state-space scan (rank-32 kernel) instead of FFT conv.
//   K1 setup : per (h,n) mode tables in double; p-dimension split 8-way per
//              thread via binary-power jump-in (parallelism 128->1024 waves).
//   K2 local : per-chunk local state sums Lsum[b,h,c,n].
//   K3 scan  : S[c] = dA^T S[c-1] + Lsum[c-1]  (in-place, 64 steps).
//   K4 main  : y = Re(E[t]*S_c) + intra Toeplitz + D*u + dCB*u*u_prev, gelu.
//   K5 out   : out[b,o,l] = sum_h W[o,h]*YG[b,h,l] + bias[o]
//              o-tile=8/thread, 2048 blocks -> 32 waves/CU (was 8, latency-bound).

#define H 256
#define LSEQ 4096
#define NB 4
#define NMODES 32
#define T 64
#define NC 64   // LSEQ / T

__global__ __launch_bounds__(256) void k_setup(
    const float* __restrict__ log_dt, const float* __restrict__ w_re, const float* __restrict__ w_im,
    const float* __restrict__ B_re, const float* __restrict__ B_im,
    const float* __restrict__ C_re, const float* __restrict__ C_im,
    float2* __restrict__ P, float2* __restrict__ E, float* __restrict__ kshort,
    float2* __restrict__ dAT, float* __restrict__ dCB)
{
    int tid = threadIdx.x;
    int h = blockIdx.x;
    int n = tid & 31;
    int pg = tid >> 5;                 // 8 groups of 8 consecutive p
    int hn = h * NMODES + n;

    double dt = exp((double)log_dt[h]);
    double zr = 0.5 * dt * (double)w_re[hn], zi = 0.5 * dt * (double)w_im[hn];
    double dr = 1.0 - zr, di = -zi;
    double dn = dr * dr + di * di;
    double nr = 1.0 + zr, ni = zi;
    double dAr = (nr * dr + ni * di) / dn, dAi = (ni * dr - nr * di) / dn;
    double tbr = dt * (double)B_re[hn], tbi = dt * (double)B_im[hn];
    double dBr = (tbr * dr + tbi * di) / dn, dBi = (tbi * dr - tbr * di) / dn;
    double Cr = (double)C_re[hn], Ci = (double)C_im[hn];
    double CBr = Cr * dBr - Ci * dBi, CBi = Cr * dBi + Ci * dBr;

    // jump-in: cur = dA^(pg*8) via squarings
    double d2r = dAr*dAr - dAi*dAi,  d2i = 2.0*dAr*dAi;
    double d4r = d2r*d2r - d2i*d2i,  d4i = 2.0*d2r*d2i;
    double d8r = d4r*d4r - d4i*d4i,  d8i = 2.0*d4r*d4i;
    double d16r= d8r*d8r - d8i*d8i,  d16i= 2.0*d8r*d8i;
    double d32r= d16r*d16r - d16i*d16i, d32i = 2.0*d16r*d16i;
    double ar = 1.0, ai = 0.0;
    if (pg & 1) { double t0 = ar*d8r - ai*d8i;  ai = ar*d8i + ai*d8r;  ar = t0; }
    if (pg & 2) { double t0 = ar*d16r - ai*d16i; ai = ar*d16i + ai*d16r; ar = t0; }
    if (pg & 4) { double t0 = ar*d32r - ai*d32i; ai = ar*d32i + ai*d32r; ar = t0; }

    #pragma unroll
    for (int i = 0; i < 8; ++i) {
        int p = pg * 8 + i;
        // P[h][p][n] = dB * dA^p
        double pr = dBr * ar - dBi * ai, pi = dBr * ai + dBi * ar;
        P[(h * T + p) * NMODES + n] = make_float2((float)pr, (float)pi);
        // kshort[h][p] = 2 * Re(sum_n C*dB*dA^p)
        double q = CBr * ar - CBi * ai;
        #pragma unroll
        for (int m = 16; m >= 1; m >>= 1) q += __shfl_xor(q, m);
        if (n == 0) kshort[h * T + p] = (float)(2.0 * q);
        // advance: dA^(p+1)
        double nar = ar * dAr - ai * dAi;
        ai = ar * dAi + ai * dAr; ar = nar;
        // E[h][n][p] = 2*C*dA^(p+1)
        double er = 2.0 * (Cr * ar - Ci * ai), ei = 2.0 * (Cr * ai + Ci * ar);
        E[(h * NMODES + n) * T + p] = make_float2((float)er, (float)ei);
    }
    if (pg == 7) dAT[hn] = make_float2((float)ar, (float)ai);   // dA^64
    if (pg == 0) {
        double s1 = dBr, s2 = CBr;
        #pragma unroll
        for (int m = 16; m >= 1; m >>= 1) { s1 += __shfl_xor(s1, m); s2 += __shfl_xor(s2, m); }
        if (n == 0) dCB[h] = (float)(4.0 * s1 * s2);
    }
}

// Lsum[b,h,c,n] = sum_{j=0}^{T-1} P[h][T-1-j][n] * u[b,h,c*T+j]
__global__ __launch_bounds__(256) void k_local(
    const float* __restrict__ u, const float2* __restrict__ P, float2* __restrict__ SL)
{
    int tid = threadIdx.x;
    int n = tid & 31, csub = tid >> 5;           // 8 chunks per block
    int bh = blockIdx.x >> 3;                    // b*H + h
    int c = ((blockIdx.x & 7) << 3) + csub;
    int h = bh & (H - 1);
    const float* ub = u + bh * LSEQ + c * T;
    const float2* Ph = P + h * T * NMODES + n;
    float2 acc = make_float2(0.f, 0.f);
    #pragma unroll 8
    for (int j = 0; j < T; ++j) {
        float uv = ub[j];
        float2 p = Ph[(T - 1 - j) * NMODES];
        acc.x += p.x * uv; acc.y += p.y * uv;
    }
    SL[(bh * NC + c) * NMODES + n] = acc;
}

// in-place scan: slot c gets state entering chunk c; S_0 = 0
__global__ __launch_bounds__(256) void k_scan(
    const float2* __restrict__ dAT, float2* __restrict__ SL)
{
    int gid = blockIdx.x * 256 + threadIdx.x;    // (b*H+h)*32 + n
    int n = gid & 31;
    int bh = gid >> 5;
    int h = bh & (H - 1);
    float2 A = dAT[h * NMODES + n];
    float2 S = make_float2(0.f, 0.f);
    float2* base = SL + (size_t)bh * NC * NMODES + n;
    for (int c = 0; c < NC; ++c) {
        float2 tmp = base[c * NMODES];
        base[c * NMODES] = S;
        float sr = S.x * A.x - S.y * A.y + tmp.x;
        float si = S.x * A.y + S.y * A.x + tmp.y;
        S = make_float2(sr, si);
    }
}

__global__ __launch_bounds__(256) void k_main(
    const float* __restrict__ u, const float2* __restrict__ E,
    const float* __restrict__ kshort, const float2* __restrict__ SL,
    const float* __restrict__ dCB, const float* __restrict__ D,
    float* __restrict__ YG)
{
    __shared__ float u_s[4][66];
    int tid = threadIdx.x;
    int t = tid & 63, csub = tid >> 6;           // one chunk per wave
    int bh = blockIdx.x >> 4;                    // 4 chunks per block
    int c = ((blockIdx.x & 15) << 2) + csub;
    int h = bh & (H - 1);
    int l0 = c * T;
    const float* ub = u + bh * LSEQ;

    u_s[csub][t + 1] = ub[l0 + t];
    if (t == 0) u_s[csub][0] = (l0 == 0) ? 0.f : ub[l0 - 1];
    __syncthreads();

    // boundary: Re( sum_n E[h][n][t] * S[b,h,c,n] )
    float bacc = 0.f;
    const float2* Eh = E + (size_t)(h * NMODES) * T + t;
    const float2* Sc = SL + (size_t)(bh * NC + c) * NMODES;
    #pragma unroll 8
    for (int n = 0; n < NMODES; ++n) {
        float2 e = Eh[n * T];
        float2 s = Sc[n];
        bacc += e.x * s.x - e.y * s.y;
    }
    // intra-chunk Toeplitz: sum_{d=0}^{t} kshort[h][d] * u[l-d]
    // fixed trip count, predicated (no exec-mask divergence)
    float iacc = 0.f;
    const float* ks = kshort + h * T;
    const float* uc = &u_s[csub][1];
    #pragma unroll 4
    for (int d = 0; d < T; ++d) {
        float uval = uc[(t - d) & 63];
        iacc += (d <= t) ? ks[d] * uval : 0.f;
    }

    float uv = uc[t];
    float up = u_s[csub][t];   // u[l-1] (0 at l==0)
    float y = bacc + iacc + D[h] * uv + dCB[h] * uv * up;
    // gelu, tanh approximation (JAX default approximate=True)
    float y3 = y * y * y;
    float g = 0.5f * y * (1.f + tanhf(0.7978845608028654f * (y + 0.044715f * y3)));
    YG[(size_t)bh * LSEQ + l0 + t] = g;
}

// out[b,o,l] = sum_h W[o,h] * YG[b,h,l] + bias[o]
// o-tile = 8 per thread, grid = (16, 32, 4) = 2048 blocks -> 32 waves/CU.
__global__ __launch_bounds__(256) void k_out(
    const float* __restrict__ YG, const float* __restrict__ W,
    const float* __restrict__ bias, float* __restrict__ out)
{
    int tid = threadIdx.x;
    int ltile = blockIdx.x;                      // 16
    int og = blockIdx.y;                         // 32 groups of 8 outputs
    int b = blockIdx.z;                          // 4
    int l = ltile * 256 + tid;

    float acc[8];
    #pragma unroll
    for (int o = 0; o < 8; ++o) acc[o] = 0.f;

    for (int hs = 0; hs < 8; ++hs) {
        float v[32];
        #pragma unroll
        for (int hh = 0; hh < 32; ++hh)
            v[hh] = YG[(size_t)(b * H + hs * 32 + hh) * LSEQ + l];  // coalesced
        #pragma unroll
        for (int o = 0; o < 8; ++o) {
            const float* Wrow = W + (size_t)(og * 8 + o) * H + hs * 32;  // wave-uniform -> s_load
            float a = acc[o];
            #pragma unroll
            for (int hh = 0; hh < 32; ++hh) a += Wrow[hh] * v[hh];
            acc[o] = a;
        }
    }
    #pragma unroll
    for (int o = 0; o < 8; ++o)
        out[(size_t)(b * H + og * 8 + o) * LSEQ + l] = acc[o] + bias[og * 8 + o];
}

extern "C" void kernel_launch(void* const* d_in, const int* in_sizes, int n_in,
                              void* d_out, int out_size, void* d_ws, size_t ws_size,
                              hipStream_t stream) {
    const float* u      = (const float*)d_in[0];
    const float* log_dt = (const float*)d_in[1];
    const float* w_re   = (const float*)d_in[2];
    const float* w_im   = (const float*)d_in[3];
    const float* B_re   = (const float*)d_in[4];
    const float* B_im   = (const float*)d_in[5];
    const float* C_re   = (const float*)d_in[6];
    const float* C_im   = (const float*)d_in[7];
    const float* Dp     = (const float*)d_in[8];
    const float* Wp     = (const float*)d_in[9];
    const float* bias   = (const float*)d_in[10];
    float* out = (float*)d_out;
    float* ws = (float*)d_ws;

    // workspace layout (float offsets)
    float2* P      = (float2*)(ws);                    // H*T*NMODES cplx = 1,048,576 f
    float2* E      = (float2*)(ws + 1048576);          // 1,048,576 f
    float* kshort  = ws + 2097152;                     // 16,384 f
    float2* dAT    = (float2*)(ws + 2113536);          // 16,384 f
    float* dCB     = ws + 2129920;                     // 256 f
    float2* SL     = (float2*)(ws + 2130176);          // B*H*NC*NMODES cplx = 4,194,304 f
    float* YG      = ws + 2130176 + 4194304;           // 4,194,304 f
    // total = 10,518,784 floats = 42.1 MB

    k_setup<<<H, 256, 0, stream>>>(log_dt, w_re, w_im, B_re, B_im, C_re, C_im,
                                   P, E, kshort, dAT, dCB);
    k_local<<<NB * H * 8, 256, 0, stream>>>(u, P, SL);
    k_scan<<<NB * H * NMODES / 256, 256, 0, stream>>>(dAT, SL);
    k_main<<<NB * H * 16, 256, 0, stream>>>(u, E, kshort, SL, dCB, Dp, YG);
    dim3 g5(LSEQ / 256, 32, NB);
    k_out<<<g5, 256, 0, stream>>>(YG, Wp, bias, out);
}

// Round 5
// 210.802 us; speedup vs baseline: 2.0563x; 1.5155x over previous
//
#include <hip/hip_runtime.h>
#include <math.h>

// S4 liquid forward. B=4, H=256, L=4096, N2=32, C=1.
// Chunked state-space scan; the per-h chunk compute and the output linear are
// f16 MFMA GEMMs (16x16x32), everything state-carrying (local sums, scan)
// stays fp32 (scan amplifies injected error ~1/(1-|dA|^64) ~ 30x).
//   K1 setup : mode tables (double); builds Mh[h][64t][128k] f16 where
//              Mh = [Toeplitz(kshort) | E_re | E_im]; P (fp32) for k_local;
//              dA^T, dCB; converts W -> f16.
//   K2 local : fp32 per-chunk local state sums (planar re/im).
//   K3 scan  : in-place fp32: slot c <- state entering chunk c (im negated).
//   K4 main  : per h: Y = Mh(64x128) x V(128x256q) via MFMA, V = [u | Sre | -Sim];
//              epilogue D*u + dCB*u*uprev + gelu -> YG fp32.
//   K5 out   : out = W(256x256) x YG(256x16384) via MFMA + bias.

#define H 256
#define LSEQ 4096
#define NB 4
#define NMODES 32
#define T 64
#define NC 64   // LSEQ / T

typedef _Float16 f16;
typedef _Float16 f16x2 __attribute__((ext_vector_type(2)));
typedef _Float16 f16x8 __attribute__((ext_vector_type(8)));
typedef float f32x4 __attribute__((ext_vector_type(4)));
union U16x8 { f16x8 v; f16x2 h[4]; uint4 q; };

// cvt_pkrtz returns __fp16x2; bit-cast to _Float16x2
static __device__ __forceinline__ f16x2 pk(float a, float b) {
    typedef __fp16 fp16x2n __attribute__((ext_vector_type(2)));
    fp16x2n r = __builtin_amdgcn_cvt_pkrtz(a, b);
    return __builtin_bit_cast(f16x2, r);
}

__global__ __launch_bounds__(256) void k_setup(
    const float* __restrict__ log_dt, const float* __restrict__ w_re, const float* __restrict__ w_im,
    const float* __restrict__ B_re, const float* __restrict__ B_im,
    const float* __restrict__ C_re, const float* __restrict__ C_im,
    const float* __restrict__ W,
    float2* __restrict__ P, f16* __restrict__ Mh, f16* __restrict__ Wh,
    float2* __restrict__ dAT, float* __restrict__ dCB)
{
    __shared__ float ks_lds[T];
    __shared__ float ERe_lds[NMODES * T];
    __shared__ float EIm_lds[NMODES * T];

    int tid = threadIdx.x;
    int h = blockIdx.x;
    int n = tid & 31;
    int pg = tid >> 5;                 // 8 groups of 8 consecutive p
    int hn = h * NMODES + n;

    // W -> f16 (independent)
    Wh[h * 256 + tid] = (f16)W[h * 256 + tid];

    double dt = exp((double)log_dt[h]);
    double zr = 0.5 * dt * (double)w_re[hn], zi = 0.5 * dt * (double)w_im[hn];
    double dr = 1.0 - zr, di = -zi;
    double dn = dr * dr + di * di;
    double nr = 1.0 + zr, ni = zi;
    double dAr = (nr * dr + ni * di) / dn, dAi = (ni * dr - nr * di) / dn;
    double tbr = dt * (double)B_re[hn], tbi = dt * (double)B_im[hn];
    double dBr = (tbr * dr + tbi * di) / dn, dBi = (tbi * dr - tbr * di) / dn;
    double Cr = (double)C_re[hn], Ci = (double)C_im[hn];
    double CBr = Cr * dBr - Ci * dBi, CBi = Cr * dBi + Ci * dBr;

    // jump-in: dA^(pg*8) via squarings
    double d2r = dAr*dAr - dAi*dAi,  d2i = 2.0*dAr*dAi;
    double d4r = d2r*d2r - d2i*d2i,  d4i = 2.0*d2r*d2i;
    double d8r = d4r*d4r - d4i*d4i,  d8i = 2.0*d4r*d4i;
    double d16r= d8r*d8r - d8i*d8i,  d16i= 2.0*d8r*d8i;
    double d32r= d16r*d16r - d16i*d16i, d32i = 2.0*d16r*d16i;
    double ar = 1.0, ai = 0.0;
    if (pg & 1) { double t0 = ar*d8r - ai*d8i;  ai = ar*d8i + ai*d8r;  ar = t0; }
    if (pg & 2) { double t0 = ar*d16r - ai*d16i; ai = ar*d16i + ai*d16r; ar = t0; }
    if (pg & 4) { double t0 = ar*d32r - ai*d32i; ai = ar*d32i + ai*d32r; ar = t0; }

    #pragma unroll
    for (int i = 0; i < 8; ++i) {
        int p = pg * 8 + i;
        double pr = dBr * ar - dBi * ai, pi = dBr * ai + dBi * ar;
        P[(h * T + p) * NMODES + n] = make_float2((float)pr, (float)pi);
        double q = CBr * ar - CBi * ai;
        #pragma unroll
        for (int m = 16; m >= 1; m >>= 1) q += __shfl_xor(q, m);
        if (n == 0) ks_lds[p] = (float)(2.0 * q);
        double nar = ar * dAr - ai * dAi;
        ai = ar * dAi + ai * dAr; ar = nar;
        ERe_lds[n * T + p] = (float)(2.0 * (Cr * ar - Ci * ai));
        EIm_lds[n * T + p] = (float)(2.0 * (Cr * ai + Ci * ar));
    }
    if (pg == 7) dAT[hn] = make_float2((float)ar, (float)ai);   // dA^64
    if (pg == 0) {
        double s1 = dBr, s2 = CBr;
        #pragma unroll
        for (int m = 16; m >= 1; m >>= 1) { s1 += __shfl_xor(s1, m); s2 += __shfl_xor(s2, m); }
        if (n == 0) dCB[h] = (float)(4.0 * s1 * s2);
    }
    __syncthreads();

    // phase 2: Mh[t][k]: k<64: Toeplitz kshort[t-k]; 64..95: ERe[n][t]; 96..127: EIm[n][t]
    int t = tid >> 2, kq = tid & 3;
    U16x8 w4[4];
    #pragma unroll
    for (int i = 0; i < 32; ++i) {
        int k = kq * 32 + i;
        float val;
        if (k < 64)       val = (k <= t) ? ks_lds[t - k] : 0.f;
        else if (k < 96)  val = ERe_lds[(k - 64) * T + t];
        else              val = EIm_lds[(k - 96) * T + t];
        w4[i >> 3].h[(i >> 1) & 3][i & 1] = (f16)val;
    }
    uint4* dst = (uint4*)(Mh + ((size_t)(h * T) + t) * 128 + kq * 32);
    #pragma unroll
    for (int i = 0; i < 4; ++i) dst[i] = w4[i].q;
}

// planar Lsum: SLre/SLim[(bh*NC+c)*32+n] = sum_j P[h][T-1-j][n] * u[b,h,c*T+j]
__global__ __launch_bounds__(256) void k_local(
    const float* __restrict__ u, const float2* __restrict__ P,
    float* __restrict__ SLre, float* __restrict__ SLim)
{
    int tid = threadIdx.x;
    int n = tid & 31, csub = tid >> 5;           // 8 chunks per block
    int bh = blockIdx.x >> 3;
    int c = ((blockIdx.x & 7) << 3) + csub;
    int h = bh & (H - 1);
    const float* ub = u + bh * LSEQ + c * T;
    const float2* Ph = P + h * T * NMODES + n;
    float2 acc = make_float2(0.f, 0.f);
    #pragma unroll 8
    for (int j = 0; j < T; ++j) {
        float uv = ub[j];
        float2 p = Ph[(T - 1 - j) * NMODES];
        acc.x += p.x * uv; acc.y += p.y * uv;
    }
    int idx = (bh * NC + c) * NMODES + n;
    SLre[idx] = acc.x;
    SLim[idx] = acc.y;
}

// in-place scan: slot c <- state entering chunk c (S_0 = 0); im stored negated.
__global__ __launch_bounds__(256) void k_scan(
    const float2* __restrict__ dAT, float* __restrict__ SLre, float* __restrict__ SLim)
{
    int gid = blockIdx.x * 256 + threadIdx.x;    // (b*H+h)*32 + n
    int n = gid & 31;
    int bh = gid >> 5;
    int h = bh & (H - 1);
    float2 A = dAT[h * NMODES + n];
    float Sr = 0.f, Si = 0.f;
    size_t base = (size_t)bh * NC * NMODES + n;
    for (int c = 0; c < NC; ++c) {
        size_t idx = base + c * NMODES;
        float lr = SLre[idx], li = SLim[idx];
        SLre[idx] = Sr;
        SLim[idx] = -Si;
        float nsr = Sr * A.x - Si * A.y + lr;
        Si = Sr * A.y + Si * A.x + li;
        Sr = nsr;
    }
}

// per h: Y(64t x 256q) = Mh(64x128) x V(128x256), V = [u(64) | Sre(32) | -Sim(32)]
// one block per h; wave w owns q-range [w*64, w*64+64); acc[tt][qt] 16x16 tiles.
__global__ __launch_bounds__(256) void k_main(
    const float* __restrict__ u, const f16* __restrict__ Mh,
    const float* __restrict__ SLre, const float* __restrict__ SLim,
    const float* __restrict__ dCB, const float* __restrict__ D,
    float* __restrict__ YG)
{
    int h = blockIdx.x;
    int tid = threadIdx.x;
    int w = tid >> 6, lane = tid & 63;
    int l15 = lane & 15, g = lane >> 4;

    f32x4 acc[4][4];
    #pragma unroll
    for (int i = 0; i < 4; ++i)
        #pragma unroll
        for (int j = 0; j < 4; ++j) acc[i][j] = (f32x4)0.f;

    const f16* Mbase = Mh + (size_t)h * T * 128;

    #pragma unroll
    for (int s = 0; s < 4; ++s) {
        // A-frags: 4 t-tiles; lane: row t = tt*16 + l15, k = 32s + 8g + e
        f16x8 a4[4];
        #pragma unroll
        for (int tt = 0; tt < 4; ++tt)
            a4[tt] = *(const f16x8*)(Mbase + (tt * 16 + l15) * 128 + 32 * s + 8 * g);

        #pragma unroll
        for (int qt = 0; qt < 4; ++qt) {
            int q = w * 64 + qt * 16 + l15;
            int b = q >> 6, c = q & 63;
            U16x8 bf;
            f32x4 lo, hi;
            if (s < 2) {
                int j0 = 32 * s + 8 * g;
                const float* up = u + ((size_t)(b * H + h)) * LSEQ + c * T + j0;
                lo = *(const f32x4*)up;
                hi = *(const f32x4*)(up + 4);
            } else {
                int n0 = 8 * g;
                const float* sp = (s == 2 ? SLre : SLim) +
                                  ((size_t)(b * H + h) * NC + c) * NMODES + n0;
                lo = *(const f32x4*)sp;
                hi = *(const f32x4*)(sp + 4);
            }
            bf.h[0] = pk(lo.x, lo.y);
            bf.h[1] = pk(lo.z, lo.w);
            bf.h[2] = pk(hi.x, hi.y);
            bf.h[3] = pk(hi.z, hi.w);
            #pragma unroll
            for (int tt = 0; tt < 4; ++tt)
                acc[tt][qt] = __builtin_amdgcn_mfma_f32_16x16x32_f16(a4[tt], bf.v, acc[tt][qt], 0, 0, 0);
        }
    }

    // epilogue: D-skip + liquid + gelu; D row t = tt*16 + g*4 + r, col q = qt*16+l15
    float Dh = D[h], dCBh = dCB[h];
    #pragma unroll
    for (int tt = 0; tt < 4; ++tt) {
        #pragma unroll
        for (int qt = 0; qt < 4; ++qt) {
            int q = w * 64 + qt * 16 + l15;
            int b = q >> 6, c = q & 63;
            int l0 = c * T + tt * 16 + g * 4;
            const float* ub = u + ((size_t)(b * H + h)) * LSEQ;
            f32x4 uv = *(const f32x4*)(ub + l0);
            float up0 = (l0 == 0) ? 0.f : ub[l0 - 1];
            float ups[4] = {up0, uv.x, uv.y, uv.z};
            f32x4 out4;
            #pragma unroll
            for (int r = 0; r < 4; ++r) {
                float y = acc[tt][qt][r] + Dh * uv[r] + dCBh * uv[r] * ups[r];
                float y3 = y * y * y;
                out4[r] = 0.5f * y * (1.f + tanhf(0.7978845608028654f * (y + 0.044715f * y3)));
            }
            *(f32x4*)(YG + ((size_t)(b * H + h)) * LSEQ + l0) = out4;
        }
    }
}

// out(256o x 16384L) = Wh(256x256) x YG + bias. Block: 32o x 256L; wave:
// ot = w>>1 (16 o), Lhalf = w&1 (128 L = 8 tiles). A k-contig from Wh.
__global__ __launch_bounds__(256) void k_out(
    const float* __restrict__ YG, const f16* __restrict__ Wh,
    const float* __restrict__ bias, float* __restrict__ out)
{
    int tid = threadIdx.x;
    int w = tid >> 6, lane = tid & 63;
    int l15 = lane & 15, g = lane >> 4;
    int o0 = blockIdx.y * 32 + (w >> 1) * 16;
    int Lbase = blockIdx.x * 256 + (w & 1) * 128;

    // preload 8 A-frags: row o = o0 + l15, k(h) = 32s + 8g + e
    f16x8 a8[8];
    #pragma unroll
    for (int s = 0; s < 8; ++s)
        a8[s] = *(const f16x8*)(Wh + (size_t)(o0 + l15) * 256 + 32 * s + 8 * g);

    f32x4 acc[8];
    #pragma unroll
    for (int i = 0; i < 8; ++i) acc[i] = (f32x4)0.f;

    #pragma unroll
    for (int s = 0; s < 8; ++s) {
        int h0 = 32 * s + 8 * g;
        #pragma unroll
        for (int lt = 0; lt < 8; ++lt) {
            int L = Lbase + lt * 16 + l15;
            int b = L >> 12, l = L & 4095;
            const float* yp = YG + (size_t)b * (H * LSEQ) + (size_t)h0 * LSEQ + l;
            float v0 = yp[0];
            float v1 = yp[LSEQ];
            float v2 = yp[2 * LSEQ];
            float v3 = yp[3 * LSEQ];
            float v4 = yp[4 * LSEQ];
            float v5 = yp[5 * LSEQ];
            float v6 = yp[6 * LSEQ];
            float v7 = yp[7 * LSEQ];
            U16x8 bf;
            bf.h[0] = pk(v0, v1);
            bf.h[1] = pk(v2, v3);
            bf.h[2] = pk(v4, v5);
            bf.h[3] = pk(v6, v7);
            acc[lt] = __builtin_amdgcn_mfma_f32_16x16x32_f16(a8[s], bf.v, acc[lt], 0, 0, 0);
        }
    }

    #pragma unroll
    for (int lt = 0; lt < 8; ++lt) {
        int L = Lbase + lt * 16 + l15;
        int b = L >> 12, l = L & 4095;
        #pragma unroll
        for (int r = 0; r < 4; ++r) {
            int o = o0 + g * 4 + r;
            out[((size_t)(b * 256 + o)) * LSEQ + l] = acc[lt][r] + bias[o];
        }
    }
}

extern "C" void kernel_launch(void* const* d_in, const int* in_sizes, int n_in,
                              void* d_out, int out_size, void* d_ws, size_t ws_size,
                              hipStream_t stream) {
    const float* u      = (const float*)d_in[0];
    const float* log_dt = (const float*)d_in[1];
    const float* w_re   = (const float*)d_in[2];
    const float* w_im   = (const float*)d_in[3];
    const float* B_re   = (const float*)d_in[4];
    const float* B_im   = (const float*)d_in[5];
    const float* C_re   = (const float*)d_in[6];
    const float* C_im   = (const float*)d_in[7];
    const float* Dp     = (const float*)d_in[8];
    const float* Wp     = (const float*)d_in[9];
    const float* bias   = (const float*)d_in[10];
    float* out = (float*)d_out;
    float* ws = (float*)d_ws;

    // workspace (float offsets): total 10,535,168 floats = 42.1 MB
    float2* P    = (float2*)(ws);                 // [0, 1048576)
    f16*    Mh   = (f16*)(ws + 1048576);          // [1048576, 2097152)
    f16*    Wh   = (f16*)(ws + 2097152);          // [2097152, 2129920)
    float2* dAT  = (float2*)(ws + 2129920);       // [2129920, 2146304)
    float*  dCB  = ws + 2146304;                  // [2146304, 2146560)
    float*  SLre = ws + 2146560;                  // [2146560, 4243712)
    float*  SLim = ws + 4243712;                  // [4243712, 6340864)
    float*  YG   = ws + 6340864;                  // [6340864, 10535168)

    k_setup<<<H, 256, 0, stream>>>(log_dt, w_re, w_im, B_re, B_im, C_re, C_im,
                                   Wp, P, Mh, Wh, dAT, dCB);
    k_local<<<NB * H * 8, 256, 0, stream>>>(u, P, SLre, SLim);
    k_scan<<<NB * H * NMODES / 256, 256, 0, stream>>>(dAT, SLre, SLim);
    k_main<<<H, 256, 0, stream>>>(u, Mh, SLre, SLim, dCB, Dp, YG);
    dim3 g5(LSEQ * NB / 256, H / 32);
    k_out<<<g5, 256, 0, stream>>>(YG, Wh, bias, out);
}

// Round 6
// 149.818 us; speedup vs baseline: 2.8933x; 1.4071x over previous
//
#include <hip/hip_runtime.h>
#include <math.h>

// S4 liquid forward. B=4, H=256, L=4096, N2=32, C=1.
// Chunked state-space scan; per-h chunk compute and output linear are f16 MFMA
// GEMMs (fp32 accum); state-carrying local sums + scan stay fp32.
//   K1 setup : mode tables (double), 512 thr: Mh[h][64t][128k] f16, P fp32,
//              dA^T, dCB, W->f16.
//   K2 local : LDS-staged u, float4 P loads; Lsum planar re/im (fp32).
//   K3 scanA : per-segment (16 chunks) local scan + carry.  [2-level scan]
//   K3 scanB : Horner carry combine + A^r fixup walk (im negated).
//   K4 main  : per h: Y = Mh(64x128) x V(128x256) MFMA; epilogue + gelu -> YG.
//   K5 out   : out = Wh(256x256) x YG(256x16384) MFMA + bias.

#define H 256
#define LSEQ 4096
#define NB 4
#define NMODES 32
#define T 64
#define NC 64   // LSEQ / T
#define NSEG 4
#define SEGC 16 // NC / NSEG

typedef _Float16 f16;
typedef _Float16 f16x2 __attribute__((ext_vector_type(2)));
typedef _Float16 f16x8 __attribute__((ext_vector_type(8)));
typedef float f32x4 __attribute__((ext_vector_type(4)));
union U16x8 { f16x8 v; f16x2 h[4]; uint4 q; };

// cvt_pkrtz returns __fp16x2; bit-cast to _Float16x2
static __device__ __forceinline__ f16x2 pk(float a, float b) {
    typedef __fp16 fp16x2n __attribute__((ext_vector_type(2)));
    fp16x2n r = __builtin_amdgcn_cvt_pkrtz(a, b);
    return __builtin_bit_cast(f16x2, r);
}

__global__ __launch_bounds__(512) void k_setup(
    const float* __restrict__ log_dt, const float* __restrict__ w_re, const float* __restrict__ w_im,
    const float* __restrict__ B_re, const float* __restrict__ B_im,
    const float* __restrict__ C_re, const float* __restrict__ C_im,
    const float* __restrict__ W,
    float2* __restrict__ P, f16* __restrict__ Mh, f16* __restrict__ Wh,
    float2* __restrict__ dAT, float* __restrict__ dCB)
{
    __shared__ float ks_lds[T];
    __shared__ float ERe_lds[NMODES * T];
    __shared__ float EIm_lds[NMODES * T];

    int tid = threadIdx.x;
    int h = blockIdx.x;
    int n = tid & 31;
    int pg = tid >> 5;                 // 16 groups of 4 consecutive p
    int hn = h * NMODES + n;

    if (tid < 256) Wh[h * 256 + tid] = (f16)W[h * 256 + tid];

    double dt = exp((double)log_dt[h]);
    double zr = 0.5 * dt * (double)w_re[hn], zi = 0.5 * dt * (double)w_im[hn];
    double dr = 1.0 - zr, di = -zi;
    double dn = dr * dr + di * di;
    double nr = 1.0 + zr, ni = zi;
    double dAr = (nr * dr + ni * di) / dn, dAi = (ni * dr - nr * di) / dn;
    double tbr = dt * (double)B_re[hn], tbi = dt * (double)B_im[hn];
    double dBr = (tbr * dr + tbi * di) / dn, dBi = (tbi * dr - tbr * di) / dn;
    double Cr = (double)C_re[hn], Ci = (double)C_im[hn];
    double CBr = Cr * dBr - Ci * dBi, CBi = Cr * dBi + Ci * dBr;

    // jump-in: dA^(pg*4) via squarings (need dA^4,8,16,32)
    double d2r = dAr*dAr - dAi*dAi,  d2i = 2.0*dAr*dAi;
    double d4r = d2r*d2r - d2i*d2i,  d4i = 2.0*d2r*d2i;
    double d8r = d4r*d4r - d4i*d4i,  d8i = 2.0*d4r*d4i;
    double d16r= d8r*d8r - d8i*d8i,  d16i= 2.0*d8r*d8i;
    double d32r= d16r*d16r - d16i*d16i, d32i = 2.0*d16r*d16i;
    double ar = 1.0, ai = 0.0;
    if (pg & 1) { double t0 = ar*d4r - ai*d4i;  ai = ar*d4i + ai*d4r;  ar = t0; }
    if (pg & 2) { double t0 = ar*d8r - ai*d8i;  ai = ar*d8i + ai*d8r;  ar = t0; }
    if (pg & 4) { double t0 = ar*d16r - ai*d16i; ai = ar*d16i + ai*d16r; ar = t0; }
    if (pg & 8) { double t0 = ar*d32r - ai*d32i; ai = ar*d32i + ai*d32r; ar = t0; }

    #pragma unroll
    for (int i = 0; i < 4; ++i) {
        int p = pg * 4 + i;
        double pr = dBr * ar - dBi * ai, pi = dBr * ai + dBi * ar;
        P[(h * T + p) * NMODES + n] = make_float2((float)pr, (float)pi);
        float q = (float)(CBr * ar - CBi * ai);
        #pragma unroll
        for (int m = 16; m >= 1; m >>= 1) q += __shfl_xor(q, m);
        if (n == 0) ks_lds[p] = 2.0f * q;
        double nar = ar * dAr - ai * dAi;
        ai = ar * dAi + ai * dAr; ar = nar;
        ERe_lds[n * T + p] = (float)(2.0 * (Cr * ar - Ci * ai));
        EIm_lds[n * T + p] = (float)(2.0 * (Cr * ai + Ci * ar));
    }
    if (pg == 15) dAT[hn] = make_float2((float)ar, (float)ai);   // dA^64
    if (pg == 0) {
        float s1 = (float)dBr, s2 = (float)CBr;
        #pragma unroll
        for (int m = 16; m >= 1; m >>= 1) { s1 += __shfl_xor(s1, m); s2 += __shfl_xor(s2, m); }
        if (n == 0) dCB[h] = 4.0f * s1 * s2;
    }
    __syncthreads();

    // phase 2: Mh[t][k]: k<64: Toeplitz kshort[t-k]; 64..95: ERe[n][t]; 96..127: EIm[n][t]
    int t = tid >> 3, kq = tid & 7;    // 8 groups of 16 k
    U16x8 w4[2];
    #pragma unroll
    for (int i = 0; i < 16; ++i) {
        int k = kq * 16 + i;
        float val;
        if (k < 64)       val = (k <= t) ? ks_lds[t - k] : 0.f;
        else if (k < 96)  val = ERe_lds[(k - 64) * T + t];
        else              val = EIm_lds[(k - 96) * T + t];
        w4[i >> 3].h[(i >> 1) & 3][i & 1] = (f16)val;
    }
    uint4* dst = (uint4*)(Mh + ((size_t)(h * T) + t) * 128 + kq * 16);
    dst[0] = w4[0].q;
    dst[1] = w4[1].q;
}

// one block per (b,h): stage u in LDS; thread = (mode-pair n16, 4 chunks);
// P read as float4 per j (2 complex modes), quarter-wave broadcast.
__global__ __launch_bounds__(256) void k_local(
    const float* __restrict__ u, const float2* __restrict__ P,
    float* __restrict__ SLre, float* __restrict__ SLim)
{
    __shared__ float u_s[64 * 68];               // stride 68: 16B-aligned, 2-way banks
    int tid = threadIdx.x;
    int bh = blockIdx.x;
    int h = bh & (H - 1);

    const float4* uv4 = (const float4*)(u + (size_t)bh * LSEQ);
    #pragma unroll
    for (int it = 0; it < 4; ++it) {
        int f = tid + it * 256;                  // float4 index (1024 total)
        int c = f >> 4, j4 = (f & 15) * 4;
        *(float4*)(&u_s[c * 68 + j4]) = uv4[f];
    }
    __syncthreads();

    int n16 = tid & 15, cq = tid >> 4;           // chunks 4cq..4cq+3
    float2 acc[4][2];
    #pragma unroll
    for (int i = 0; i < 4; ++i) { acc[i][0] = make_float2(0.f,0.f); acc[i][1] = make_float2(0.f,0.f); }

    const float4* P4 = (const float4*)P;
    size_t prow = (size_t)h * T;
    #pragma unroll 4
    for (int j = 0; j < T; ++j) {
        float4 pv = P4[(prow + (T - 1 - j)) * 16 + n16];   // modes 2n16, 2n16+1
        #pragma unroll
        for (int i = 0; i < 4; ++i) {
            float uval = u_s[(cq * 4 + i) * 68 + j];
            acc[i][0].x += pv.x * uval; acc[i][0].y += pv.y * uval;
            acc[i][1].x += pv.z * uval; acc[i][1].y += pv.w * uval;
        }
    }
    #pragma unroll
    for (int i = 0; i < 4; ++i) {
        int c = cq * 4 + i;
        size_t idx = ((size_t)bh * NC + c) * NMODES + 2 * n16;
        *(float2*)(SLre + idx) = make_float2(acc[i][0].x, acc[i][1].x);
        *(float2*)(SLim + idx) = make_float2(acc[i][0].y, acc[i][1].y);
    }
}

// scan pass A: per (bh,n,seg): local scan of 16 chunks (slot <- local prefix,
// im NOT yet negated), carry = segment total.
__global__ __launch_bounds__(256) void k_scanA(
    const float2* __restrict__ dAT, float* __restrict__ SLre, float* __restrict__ SLim,
    float2* __restrict__ Carry)
{
    int gid = blockIdx.x * 256 + threadIdx.x;    // bh*128 + seg*32 + n
    int n = gid & 31;
    int seg = (gid >> 5) & 3;
    int bh = gid >> 7;
    int h = bh & (H - 1);
    float2 A = dAT[h * NMODES + n];
    float Sr = 0.f, Si = 0.f;
    size_t base = ((size_t)bh * NC + seg * SEGC) * NMODES + n;
    for (int r = 0; r < SEGC; ++r) {
        size_t idx = base + (size_t)r * NMODES;
        float lr = SLre[idx], li = SLim[idx];
        SLre[idx] = Sr; SLim[idx] = Si;
        float ns = Sr * A.x - Si * A.y + lr;
        Si = Sr * A.y + Si * A.x + li;
        Sr = ns;
    }
    Carry[((size_t)bh * NSEG + seg) * NMODES + n] = make_float2(Sr, Si);
}

// scan pass B: E_seg = Horner(carries, A16); slot <- E_seg*A^r + prefix (im negated).
__global__ __launch_bounds__(256) void k_scanB(
    const float2* __restrict__ dAT, float* __restrict__ SLre, float* __restrict__ SLim,
    const float2* __restrict__ Carry)
{
    int gid = blockIdx.x * 256 + threadIdx.x;
    int n = gid & 31;
    int seg = (gid >> 5) & 3;
    int bh = gid >> 7;
    int h = bh & (H - 1);
    float2 A = dAT[h * NMODES + n];
    // A16 = A^16 by 4 squarings
    float ar = A.x, ai = A.y;
    #pragma unroll
    for (int s = 0; s < 4; ++s) { float t = ar*ar - ai*ai; ai = 2.f*ar*ai; ar = t; }
    // E = sum_{j<seg} A16^(seg-1-j) * C_j  (Horner)
    float Er = 0.f, Ei = 0.f;
    const float2* Cb = Carry + (size_t)bh * NSEG * NMODES + n;
    for (int j = 0; j < seg; ++j) {
        float2 C = Cb[(size_t)j * NMODES];
        float t = Er * ar - Ei * ai + C.x;
        Ei = Er * ai + Ei * ar + C.y;
        Er = t;
    }
    float Vr = Er, Vi = Ei;
    size_t base = ((size_t)bh * NC + seg * SEGC) * NMODES + n;
    for (int r = 0; r < SEGC; ++r) {
        size_t idx = base + (size_t)r * NMODES;
        float lr = SLre[idx], li = SLim[idx];
        SLre[idx] = Vr + lr;
        SLim[idx] = -(Vi + li);
        float t = Vr * A.x - Vi * A.y;
        Vi = Vr * A.y + Vi * A.x;
        Vr = t;
    }
}

// per h: Y(64t x 256q) = Mh(64x128) x V(128x256), V = [u(64) | Sre(32) | -Sim(32)]
__global__ __launch_bounds__(256) void k_main(
    const float* __restrict__ u, const f16* __restrict__ Mh,
    const float* __restrict__ SLre, const float* __restrict__ SLim,
    const float* __restrict__ dCB, const float* __restrict__ D,
    float* __restrict__ YG)
{
    int h = blockIdx.x;
    int tid = threadIdx.x;
    int w = tid >> 6, lane = tid & 63;
    int l15 = lane & 15, g = lane >> 4;

    f32x4 acc[4][4];
    #pragma unroll
    for (int i = 0; i < 4; ++i)
        #pragma unroll
        for (int j = 0; j < 4; ++j) acc[i][j] = (f32x4)0.f;

    const f16* Mbase = Mh + (size_t)h * T * 128;

    #pragma unroll
    for (int s = 0; s < 4; ++s) {
        f16x8 a4[4];
        #pragma unroll
        for (int tt = 0; tt < 4; ++tt)
            a4[tt] = *(const f16x8*)(Mbase + (tt * 16 + l15) * 128 + 32 * s + 8 * g);

        #pragma unroll
        for (int qt = 0; qt < 4; ++qt) {
            int q = w * 64 + qt * 16 + l15;
            int b = q >> 6, c = q & 63;
            U16x8 bf;
            f32x4 lo, hi;
            if (s < 2) {
                int j0 = 32 * s + 8 * g;
                const float* up = u + ((size_t)(b * H + h)) * LSEQ + c * T + j0;
                lo = *(const f32x4*)up;
                hi = *(const f32x4*)(up + 4);
            } else {
                int n0 = 8 * g;
                const float* sp = (s == 2 ? SLre : SLim) +
                                  ((size_t)(b * H + h) * NC + c) * NMODES + n0;
                lo = *(const f32x4*)sp;
                hi = *(const f32x4*)(sp + 4);
            }
            bf.h[0] = pk(lo.x, lo.y);
            bf.h[1] = pk(lo.z, lo.w);
            bf.h[2] = pk(hi.x, hi.y);
            bf.h[3] = pk(hi.z, hi.w);
            #pragma unroll
            for (int tt = 0; tt < 4; ++tt)
                acc[tt][qt] = __builtin_amdgcn_mfma_f32_16x16x32_f16(a4[tt], bf.v, acc[tt][qt], 0, 0, 0);
        }
    }

    float Dh = D[h], dCBh = dCB[h];
    #pragma unroll
    for (int tt = 0; tt < 4; ++tt) {
        #pragma unroll
        for (int qt = 0; qt < 4; ++qt) {
            int q = w * 64 + qt * 16 + l15;
            int b = q >> 6, c = q & 63;
            int l0 = c * T + tt * 16 + g * 4;
            const float* ub = u + ((size_t)(b * H + h)) * LSEQ;
            f32x4 uv = *(const f32x4*)(ub + l0);
            float up0 = (l0 == 0) ? 0.f : ub[l0 - 1];
            float ups[4] = {up0, uv.x, uv.y, uv.z};
            f32x4 out4;
            #pragma unroll
            for (int r = 0; r < 4; ++r) {
                float y = acc[tt][qt][r] + Dh * uv[r] + dCBh * uv[r] * ups[r];
                float y3 = y * y * y;
                out4[r] = 0.5f * y * (1.f + tanhf(0.7978845608028654f * (y + 0.044715f * y3)));
            }
            *(f32x4*)(YG + ((size_t)(b * H + h)) * LSEQ + l0) = out4;
        }
    }
}

// out(256o x 16384L) = Wh(256x256) x YG + bias.
__global__ __launch_bounds__(256) void k_out(
    const float* __restrict__ YG, const f16* __restrict__ Wh,
    const float* __restrict__ bias, float* __restrict__ out)
{
    int tid = threadIdx.x;
    int w = tid >> 6, lane = tid & 63;
    int l15 = lane & 15, g = lane >> 4;
    int o0 = blockIdx.y * 32 + (w >> 1) * 16;
    int Lbase = blockIdx.x * 256 + (w & 1) * 128;

    f16x8 a8[8];
    #pragma unroll
    for (int s = 0; s < 8; ++s)
        a8[s] = *(const f16x8*)(Wh + (size_t)(o0 + l15) * 256 + 32 * s + 8 * g);

    f32x4 acc[8];
    #pragma unroll
    for (int i = 0; i < 8; ++i) acc[i] = (f32x4)0.f;

    #pragma unroll
    for (int s = 0; s < 8; ++s) {
        int h0 = 32 * s + 8 * g;
        #pragma unroll
        for (int lt = 0; lt < 8; ++lt) {
            int L = Lbase + lt * 16 + l15;
            int b = L >> 12, l = L & 4095;
            const float* yp = YG + (size_t)b * (H * LSEQ) + (size_t)h0 * LSEQ + l;
            float v0 = yp[0];
            float v1 = yp[LSEQ];
            float v2 = yp[2 * LSEQ];
            float v3 = yp[3 * LSEQ];
            float v4 = yp[4 * LSEQ];
            float v5 = yp[5 * LSEQ];
            float v6 = yp[6 * LSEQ];
            float v7 = yp[7 * LSEQ];
            U16x8 bf;
            bf.h[0] = pk(v0, v1);
            bf.h[1] = pk(v2, v3);
            bf.h[2] = pk(v4, v5);
            bf.h[3] = pk(v6, v7);
            acc[lt] = __builtin_amdgcn_mfma_f32_16x16x32_f16(a8[s], bf.v, acc[lt], 0, 0, 0);
        }
    }

    #pragma unroll
    for (int lt = 0; lt < 8; ++lt) {
        int L = Lbase + lt * 16 + l15;
        int b = L >> 12, l = L & 4095;
        #pragma unroll
        for (int r = 0; r < 4; ++r) {
            int o = o0 + g * 4 + r;
            out[((size_t)(b * 256 + o)) * LSEQ + l] = acc[lt][r] + bias[o];
        }
    }
}

extern "C" void kernel_launch(void* const* d_in, const int* in_sizes, int n_in,
                              void* d_out, int out_size, void* d_ws, size_t ws_size,
                              hipStream_t stream) {
    const float* u      = (const float*)d_in[0];
    const float* log_dt = (const float*)d_in[1];
    const float* w_re   = (const float*)d_in[2];
    const float* w_im   = (const float*)d_in[3];
    const float* B_re   = (const float*)d_in[4];
    const float* B_im   = (const float*)d_in[5];
    const float* C_re   = (const float*)d_in[6];
    const float* C_im   = (const float*)d_in[7];
    const float* Dp     = (const float*)d_in[8];
    const float* Wp     = (const float*)d_in[9];
    const float* bias   = (const float*)d_in[10];
    float* out = (float*)d_out;
    float* ws = (float*)d_ws;

    // workspace (float offsets): total 10,535,168 floats = 42.1 MB
    float2* P    = (float2*)(ws);                 // [0, 1048576)  (dead after k_local)
    f16*    Mh   = (f16*)(ws + 1048576);          // [1048576, 2097152)
    f16*    Wh   = (f16*)(ws + 2097152);          // [2097152, 2129920)
    float2* dAT  = (float2*)(ws + 2129920);       // [2129920, 2146304)
    float*  dCB  = ws + 2146304;                  // [2146304, 2146560)
    float*  SLre = ws + 2146560;                  // [2146560, 4243712)
    float*  SLim = ws + 4243712;                  // [4243712, 6340864)
    float*  YG   = ws + 6340864;                  // [6340864, 10535168)
    float2* Carry = (float2*)(ws);                // reuses P region (256K floats needed)

    k_setup<<<H, 512, 0, stream>>>(log_dt, w_re, w_im, B_re, B_im, C_re, C_im,
                                   Wp, P, Mh, Wh, dAT, dCB);
    k_local<<<NB * H, 256, 0, stream>>>(u, P, SLre, SLim);
    k_scanA<<<NB * H * NSEG * NMODES / 256, 256, 0, stream>>>(dAT, SLre, SLim, Carry);
    k_scanB<<<NB * H * NSEG * NMODES / 256, 256, 0, stream>>>(dAT, SLre, SLim, Carry);
    k_main<<<H, 256, 0, stream>>>(u, Mh, SLre, SLim, dCB, Dp, YG);
    dim3 g5(LSEQ * NB / 256, H / 32);
    k_out<<<g5, 256, 0, stream>>>(YG, Wh, bias, out);
}

// Round 8
// 146.872 us; speedup vs baseline: 2.9513x; 1.0201x over previous
//
#include <hip/hip_runtime.h>
#include <math.h>

// S4 liquid forward. B=4, H=256, L=4096, N2=32, C=1.
// Chunked state-space scan; per-h chunk compute and output linear are f16 MFMA
// GEMMs (fp32 accum); state-carrying local sums + scan stay fp32.
//   K1 setup : mode tables (double), 512 thr: Mh[h][64t][128k] f16, P fp32,
//              dA^T, dCB, W->f16.
//   K2 local : LDS-staged u, float4 P loads; Lsum planar re/im (fp32).
//   K3 scanA : per-segment (16 chunks) local scan + carry.  [2-level scan]
//   K3 scanB : Horner carry combine + A^r fixup walk (im negated).
//   K4 main  : per h: Y = Mh(64x128) x V(128x256) MFMA; epilogue + gelu -> YG f16
//              (same RTZ conversion k_out used to do -> identical numerics).
//   K5 out   : out = Wh(256x256) x YG16 + bias; READ-ONCE: 512 blocks of
//              256o x 32L, K-staged via LDS [32L][40] f16 (16B rows, min-conflict).

#define H 256
#define LSEQ 4096
#define NB 4
#define NMODES 32
#define T 64
#define NC 64   // LSEQ / T
#define NSEG 4
#define SEGC 16 // NC / NSEG

typedef _Float16 f16;
typedef _Float16 f16x2 __attribute__((ext_vector_type(2)));
typedef _Float16 f16x4 __attribute__((ext_vector_type(4)));
typedef _Float16 f16x8 __attribute__((ext_vector_type(8)));
typedef float f32x4 __attribute__((ext_vector_type(4)));
union U16x8 { f16x8 v; f16x2 h[4]; uint4 q; };
union U16x4 { f16x4 v; f16x2 h[2]; };

// cvt_pkrtz returns __fp16x2; bit-cast to _Float16x2
static __device__ __forceinline__ f16x2 pk(float a, float b) {
    typedef __fp16 fp16x2n __attribute__((ext_vector_type(2)));
    fp16x2n r = __builtin_amdgcn_cvt_pkrtz(a, b);
    return __builtin_bit_cast(f16x2, r);
}

__global__ __launch_bounds__(512) void k_setup(
    const float* __restrict__ log_dt, const float* __restrict__ w_re, const float* __restrict__ w_im,
    const float* __restrict__ B_re, const float* __restrict__ B_im,
    const float* __restrict__ C_re, const float* __restrict__ C_im,
    const float* __restrict__ W,
    float2* __restrict__ P, f16* __restrict__ Mh, f16* __restrict__ Wh,
    float2* __restrict__ dAT, float* __restrict__ dCB)
{
    __shared__ float ks_lds[T];
    __shared__ float ERe_lds[NMODES * T];
    __shared__ float EIm_lds[NMODES * T];

    int tid = threadIdx.x;
    int h = blockIdx.x;
    int n = tid & 31;
    int pg = tid >> 5;                 // 16 groups of 4 consecutive p
    int hn = h * NMODES + n;

    if (tid < 256) Wh[h * 256 + tid] = (f16)W[h * 256 + tid];

    double dt = exp((double)log_dt[h]);
    double zr = 0.5 * dt * (double)w_re[hn], zi = 0.5 * dt * (double)w_im[hn];
    double dr = 1.0 - zr, di = -zi;
    double dn = dr * dr + di * di;
    double nr = 1.0 + zr, ni = zi;
    double dAr = (nr * dr + ni * di) / dn, dAi = (ni * dr - nr * di) / dn;
    double tbr = dt * (double)B_re[hn], tbi = dt * (double)B_im[hn];
    double dBr = (tbr * dr + tbi * di) / dn, dBi = (tbi * dr - tbr * di) / dn;
    double Cr = (double)C_re[hn], Ci = (double)C_im[hn];
    double CBr = Cr * dBr - Ci * dBi, CBi = Cr * dBi + Ci * dBr;

    // jump-in: dA^(pg*4) via squarings (need dA^4,8,16,32)
    double d2r = dAr*dAr - dAi*dAi,  d2i = 2.0*dAr*dAi;
    double d4r = d2r*d2r - d2i*d2i,  d4i = 2.0*d2r*d2i;
    double d8r = d4r*d4r - d4i*d4i,  d8i = 2.0*d4r*d4i;
    double d16r= d8r*d8r - d8i*d8i,  d16i= 2.0*d8r*d8i;
    double d32r= d16r*d16r - d16i*d16i, d32i = 2.0*d16r*d16i;
    double ar = 1.0, ai = 0.0;
    if (pg & 1) { double t0 = ar*d4r - ai*d4i;  ai = ar*d4i + ai*d4r;  ar = t0; }
    if (pg & 2) { double t0 = ar*d8r - ai*d8i;  ai = ar*d8i + ai*d8r;  ar = t0; }
    if (pg & 4) { double t0 = ar*d16r - ai*d16i; ai = ar*d16i + ai*d16r; ar = t0; }
    if (pg & 8) { double t0 = ar*d32r - ai*d32i; ai = ar*d32i + ai*d32r; ar = t0; }

    #pragma unroll
    for (int i = 0; i < 4; ++i) {
        int p = pg * 4 + i;
        double pr = dBr * ar - dBi * ai, pi = dBr * ai + dBi * ar;
        P[(h * T + p) * NMODES + n] = make_float2((float)pr, (float)pi);
        float q = (float)(CBr * ar - CBi * ai);
        #pragma unroll
        for (int m = 16; m >= 1; m >>= 1) q += __shfl_xor(q, m);
        if (n == 0) ks_lds[p] = 2.0f * q;
        double nar = ar * dAr - ai * dAi;
        ai = ar * dAi + ai * dAr; ar = nar;
        ERe_lds[n * T + p] = (float)(2.0 * (Cr * ar - Ci * ai));
        EIm_lds[n * T + p] = (float)(2.0 * (Cr * ai + Ci * ar));
    }
    if (pg == 15) dAT[hn] = make_float2((float)ar, (float)ai);   // dA^64
    if (pg == 0) {
        float s1 = (float)dBr, s2 = (float)CBr;
        #pragma unroll
        for (int m = 16; m >= 1; m >>= 1) { s1 += __shfl_xor(s1, m); s2 += __shfl_xor(s2, m); }
        if (n == 0) dCB[h] = 4.0f * s1 * s2;
    }
    __syncthreads();

    // phase 2: Mh[t][k]: k<64: Toeplitz kshort[t-k]; 64..95: ERe[n][t]; 96..127: EIm[n][t]
    int t = tid >> 3, kq = tid & 7;    // 8 groups of 16 k
    U16x8 w4[2];
    #pragma unroll
    for (int i = 0; i < 16; ++i) {
        int k = kq * 16 + i;
        float val;
        if (k < 64)       val = (k <= t) ? ks_lds[t - k] : 0.f;
        else if (k < 96)  val = ERe_lds[(k - 64) * T + t];
        else              val = EIm_lds[(k - 96) * T + t];
        w4[i >> 3].h[(i >> 1) & 3][i & 1] = (f16)val;
    }
    uint4* dst = (uint4*)(Mh + ((size_t)(h * T) + t) * 128 + kq * 16);
    dst[0] = w4[0].q;
    dst[1] = w4[1].q;
}

// one block per (b,h): stage u in LDS; thread = (mode-pair n16, 4 chunks);
// P read as float4 per j (2 complex modes), quarter-wave broadcast.
__global__ __launch_bounds__(256) void k_local(
    const float* __restrict__ u, const float2* __restrict__ P,
    float* __restrict__ SLre, float* __restrict__ SLim)
{
    __shared__ float u_s[64 * 68];               // stride 68: 16B-aligned, 2-way banks
    int tid = threadIdx.x;
    int bh = blockIdx.x;
    int h = bh & (H - 1);

    const float4* uv4 = (const float4*)(u + (size_t)bh * LSEQ);
    #pragma unroll
    for (int it = 0; it < 4; ++it) {
        int f = tid + it * 256;                  // float4 index (1024 total)
        int c = f >> 4, j4 = (f & 15) * 4;
        *(float4*)(&u_s[c * 68 + j4]) = uv4[f];
    }
    __syncthreads();

    int n16 = tid & 15, cq = tid >> 4;           // chunks 4cq..4cq+3
    float2 acc[4][2];
    #pragma unroll
    for (int i = 0; i < 4; ++i) { acc[i][0] = make_float2(0.f,0.f); acc[i][1] = make_float2(0.f,0.f); }

    const float4* P4 = (const float4*)P;
    size_t prow = (size_t)h * T;
    #pragma unroll 4
    for (int j = 0; j < T; ++j) {
        float4 pv = P4[(prow + (T - 1 - j)) * 16 + n16];   // modes 2n16, 2n16+1
        #pragma unroll
        for (int i = 0; i < 4; ++i) {
            float uval = u_s[(cq * 4 + i) * 68 + j];
            acc[i][0].x += pv.x * uval; acc[i][0].y += pv.y * uval;
            acc[i][1].x += pv.z * uval; acc[i][1].y += pv.w * uval;
        }
    }
    #pragma unroll
    for (int i = 0; i < 4; ++i) {
        int c = cq * 4 + i;
        size_t idx = ((size_t)bh * NC + c) * NMODES + 2 * n16;
        *(float2*)(SLre + idx) = make_float2(acc[i][0].x, acc[i][1].x);
        *(float2*)(SLim + idx) = make_float2(acc[i][0].y, acc[i][1].y);
    }
}

// scan pass A: per (bh,n,seg): local scan of 16 chunks (slot <- local prefix,
// im NOT yet negated), carry = segment total.
__global__ __launch_bounds__(256) void k_scanA(
    const float2* __restrict__ dAT, float* __restrict__ SLre, float* __restrict__ SLim,
    float2* __restrict__ Carry)
{
    int gid = blockIdx.x * 256 + threadIdx.x;    // bh*128 + seg*32 + n
    int n = gid & 31;
    int seg = (gid >> 5) & 3;
    int bh = gid >> 7;
    int h = bh & (H - 1);
    float2 A = dAT[h * NMODES + n];
    float Sr = 0.f, Si = 0.f;
    size_t base = ((size_t)bh * NC + seg * SEGC) * NMODES + n;
    for (int r = 0; r < SEGC; ++r) {
        size_t idx = base + (size_t)r * NMODES;
        float lr = SLre[idx], li = SLim[idx];
        SLre[idx] = Sr; SLim[idx] = Si;
        float ns = Sr * A.x - Si * A.y + lr;
        Si = Sr * A.y + Si * A.x + li;
        Sr = ns;
    }
    Carry[((size_t)bh * NSEG + seg) * NMODES + n] = make_float2(Sr, Si);
}

// scan pass B: E_seg = Horner(carries, A16); slot <- E_seg*A^r + prefix (im negated).
__global__ __launch_bounds__(256) void k_scanB(
    const float2* __restrict__ dAT, float* __restrict__ SLre, float* __restrict__ SLim,
    const float2* __restrict__ Carry)
{
    int gid = blockIdx.x * 256 + threadIdx.x;
    int n = gid & 31;
    int seg = (gid >> 5) & 3;
    int bh = gid >> 7;
    int h = bh & (H - 1);
    float2 A = dAT[h * NMODES + n];
    // A16 = A^16 by 4 squarings
    float ar = A.x, ai = A.y;
    #pragma unroll
    for (int s = 0; s < 4; ++s) { float t = ar*ar - ai*ai; ai = 2.f*ar*ai; ar = t; }
    // E = sum_{j<seg} A16^(seg-1-j) * C_j  (Horner)
    float Er = 0.f, Ei = 0.f;
    const float2* Cb = Carry + (size_t)bh * NSEG * NMODES + n;
    for (int j = 0; j < seg; ++j) {
        float2 C = Cb[(size_t)j * NMODES];
        float t = Er * ar - Ei * ai + C.x;
        Ei = Er * ai + Ei * ar + C.y;
        Er = t;
    }
    float Vr = Er, Vi = Ei;
    size_t base = ((size_t)bh * NC + seg * SEGC) * NMODES + n;
    for (int r = 0; r < SEGC; ++r) {
        size_t idx = base + (size_t)r * NMODES;
        float lr = SLre[idx], li = SLim[idx];
        SLre[idx] = Vr + lr;
        SLim[idx] = -(Vi + li);
        float t = Vr * A.x - Vi * A.y;
        Vi = Vr * A.y + Vi * A.x;
        Vr = t;
    }
}

// per h: Y(64t x 256q) = Mh(64x128) x V(128x256), V = [u(64) | Sre(32) | -Sim(32)]
// output YG as f16 (RTZ pack — same conversion k_out's pk used to apply).
__global__ __launch_bounds__(256) void k_main(
    const float* __restrict__ u, const f16* __restrict__ Mh,
    const float* __restrict__ SLre, const float* __restrict__ SLim,
    const float* __restrict__ dCB, const float* __restrict__ D,
    f16* __restrict__ YG)
{
    int h = blockIdx.x;
    int tid = threadIdx.x;
    int w = tid >> 6, lane = tid & 63;
    int l15 = lane & 15, g = lane >> 4;

    f32x4 acc[4][4];
    #pragma unroll
    for (int i = 0; i < 4; ++i)
        #pragma unroll
        for (int j = 0; j < 4; ++j) acc[i][j] = (f32x4)0.f;

    const f16* Mbase = Mh + (size_t)h * T * 128;

    #pragma unroll
    for (int s = 0; s < 4; ++s) {
        f16x8 a4[4];
        #pragma unroll
        for (int tt = 0; tt < 4; ++tt)
            a4[tt] = *(const f16x8*)(Mbase + (tt * 16 + l15) * 128 + 32 * s + 8 * g);

        #pragma unroll
        for (int qt = 0; qt < 4; ++qt) {
            int q = w * 64 + qt * 16 + l15;
            int b = q >> 6, c = q & 63;
            U16x8 bf;
            f32x4 lo, hi;
            if (s < 2) {
                int j0 = 32 * s + 8 * g;
                const float* up = u + ((size_t)(b * H + h)) * LSEQ + c * T + j0;
                lo = *(const f32x4*)up;
                hi = *(const f32x4*)(up + 4);
            } else {
                int n0 = 8 * g;
                const float* sp = (s == 2 ? SLre : SLim) +
                                  ((size_t)(b * H + h) * NC + c) * NMODES + n0;
                lo = *(const f32x4*)sp;
                hi = *(const f32x4*)(sp + 4);
            }
            bf.h[0] = pk(lo.x, lo.y);
            bf.h[1] = pk(lo.z, lo.w);
            bf.h[2] = pk(hi.x, hi.y);
            bf.h[3] = pk(hi.z, hi.w);
            #pragma unroll
            for (int tt = 0; tt < 4; ++tt)
                acc[tt][qt] = __builtin_amdgcn_mfma_f32_16x16x32_f16(a4[tt], bf.v, acc[tt][qt], 0, 0, 0);
        }
    }

    float Dh = D[h], dCBh = dCB[h];
    #pragma unroll
    for (int tt = 0; tt < 4; ++tt) {
        #pragma unroll
        for (int qt = 0; qt < 4; ++qt) {
            int q = w * 64 + qt * 16 + l15;
            int b = q >> 6, c = q & 63;
            int l0 = c * T + tt * 16 + g * 4;
            const float* ub = u + ((size_t)(b * H + h)) * LSEQ;
            f32x4 uv = *(const f32x4*)(ub + l0);
            float up0 = (l0 == 0) ? 0.f : ub[l0 - 1];
            float ups[4] = {up0, uv.x, uv.y, uv.z};
            f32x4 out4;
            #pragma unroll
            for (int r = 0; r < 4; ++r) {
                float y = acc[tt][qt][r] + Dh * uv[r] + dCBh * uv[r] * ups[r];
                float y3 = y * y * y;
                out4[r] = 0.5f * y * (1.f + tanhf(0.7978845608028654f * (y + 0.044715f * y3)));
            }
            U16x4 o16;
            o16.h[0] = pk(out4[0], out4[1]);
            o16.h[1] = pk(out4[2], out4[3]);
            *(f16x4*)(YG + ((size_t)(b * H + h)) * LSEQ + l0) = o16.v;
        }
    }
}

// out(256o x 16384L) = Wh(256x256) x YG16 + bias; YG read ONCE.
// 512 blocks: each 256o x 32L; 4 waves, wave w: o-range [64w, 64w+64).
// K-loop 8 steps of 32 h staged to LDS [32L][40] f16 (16B rows, uniform quad-banks).
#define KO_STRIDE 40
__global__ __launch_bounds__(256) void k_out(
    const f16* __restrict__ YG, const f16* __restrict__ Wh,
    const float* __restrict__ bias, float* __restrict__ out)
{
    __shared__ f16 lds_b[32 * KO_STRIDE];
    int tid = threadIdx.x;
    int w = tid >> 6, lane = tid & 63;
    int l15 = lane & 15, g = lane >> 4;
    int Lb = blockIdx.x * 32;
    int b = Lb >> 12, lbase = Lb & 4095;
    int o0 = w * 64;

    int hh = tid >> 3, l4 = (tid & 7) * 4;       // stage mapping

    f32x4 acc[4][2];
    #pragma unroll
    for (int i = 0; i < 4; ++i) { acc[i][0] = (f32x4)0.f; acc[i][1] = (f32x4)0.f; }

    const f16* ygb = YG + ((size_t)(b * H + hh)) * LSEQ + lbase + l4;
    f16x4 v = *(const f16x4*)ygb;                // step 0 prefetch

    for (int k = 0; k < 8; ++k) {
        if (k) __syncthreads();                  // compute(k-1) done
        #pragma unroll
        for (int i = 0; i < 4; ++i) lds_b[(l4 + i) * KO_STRIDE + hh] = v[i];
        if (k < 7) v = *(const f16x4*)(ygb + (size_t)(k + 1) * 32 * LSEQ);
        __syncthreads();

        f16x8 bf[2];
        #pragma unroll
        for (int lt = 0; lt < 2; ++lt)
            bf[lt] = *(const f16x8*)(&lds_b[(lt * 16 + l15) * KO_STRIDE + 8 * g]);
        #pragma unroll
        for (int ot = 0; ot < 4; ++ot) {
            f16x8 a = *(const f16x8*)(Wh + (size_t)(o0 + ot * 16 + l15) * 256 + k * 32 + 8 * g);
            acc[ot][0] = __builtin_amdgcn_mfma_f32_16x16x32_f16(a, bf[0], acc[ot][0], 0, 0, 0);
            acc[ot][1] = __builtin_amdgcn_mfma_f32_16x16x32_f16(a, bf[1], acc[ot][1], 0, 0, 0);
        }
    }

    #pragma unroll
    for (int ot = 0; ot < 4; ++ot) {
        #pragma unroll
        for (int lt = 0; lt < 2; ++lt) {
            int l = lbase + lt * 16 + l15;
            #pragma unroll
            for (int r = 0; r < 4; ++r) {
                int o = o0 + ot * 16 + g * 4 + r;
                out[((size_t)(b * 256 + o)) * LSEQ + l] = acc[ot][lt][r] + bias[o];
            }
        }
    }
}

extern "C" void kernel_launch(void* const* d_in, const int* in_sizes, int n_in,
                              void* d_out, int out_size, void* d_ws, size_t ws_size,
                              hipStream_t stream) {
    const float* u      = (const float*)d_in[0];
    const float* log_dt = (const float*)d_in[1];
    const float* w_re   = (const float*)d_in[2];
    const float* w_im   = (const float*)d_in[3];
    const float* B_re   = (const float*)d_in[4];
    const float* B_im   = (const float*)d_in[5];
    const float* C_re   = (const float*)d_in[6];
    const float* C_im   = (const float*)d_in[7];
    const float* Dp     = (const float*)d_in[8];
    const float* Wp     = (const float*)d_in[9];
    const float* bias   = (const float*)d_in[10];
    float* out = (float*)d_out;
    float* ws = (float*)d_ws;

    // workspace (float offsets)
    float2* P    = (float2*)(ws);                 // [0, 1048576)  (dead after k_local)
    f16*    Mh   = (f16*)(ws + 1048576);          // [1048576, 2097152)
    f16*    Wh   = (f16*)(ws + 2097152);          // [2097152, 2129920)
    float2* dAT  = (float2*)(ws + 2129920);       // [2129920, 2146304)
    float*  dCB  = ws + 2146304;                  // [2146304, 2146560)
    float*  SLre = ws + 2146560;                  // [2146560, 4243712)
    float*  SLim = ws + 4243712;                  // [4243712, 6340864)
    f16*    YG16 = (f16*)(ws + 6340864);          // 4.2M f16 = 2.1M floats
    float2* Carry = (float2*)(ws);                // reuses P region (dead after k_local)

    k_setup<<<H, 512, 0, stream>>>(log_dt, w_re, w_im, B_re, B_im, C_re, C_im,
                                   Wp, P, Mh, Wh, dAT, dCB);
    k_local<<<NB * H, 256, 0, stream>>>(u, P, SLre, SLim);
    k_scanA<<<NB * H * NSEG * NMODES / 256, 256, 0, stream>>>(dAT, SLre, SLim, Carry);
    k_scanB<<<NB * H * NSEG * NMODES / 256, 256, 0, stream>>>(dAT, SLre, SLim, Carry);
    k_main<<<H, 256, 0, stream>>>(u, Mh, SLre, SLim, dCB, Dp, YG16);
    k_out<<<NB * LSEQ / 32, 256, 0, stream>>>(YG16, Wh, bias, out);
}

// Round 10
// 146.302 us; speedup vs baseline: 2.9628x; 1.0039x over previous
//
#include <hip/hip_runtime.h>
#include <math.h>

// S4 liquid forward. B=4, H=256, L=4096, N2=32, C=1.
// Chunked state-space scan; per-h chunk compute and output linear are f16 MFMA
// GEMMs (fp32 accum); state-carrying local sums + scan stay fp32.
//   K1 setup : mode tables (double), 512 thr: Mh[h][64t][128k] f16, P fp32,
//              dA^T, dCB, W->f16.
//   K2 local : LDS-staged u, float4 P loads; Lsum planar re/im (fp32).
//   K3 scanA : per-segment (16 chunks) local scan + carry.  [2-level scan]
//   K3 scanB : Horner carry combine + A^r fixup walk (im negated).
//   K4 main  : grid (H,4): Y(64t x 64q) = Mh(64x128) x V MFMA; q-split across
//              blocks for occupancy (was 1 block/CU -> 10% occ, latency-bound).
//   K5 out   : out = Wh(256x256) x YG16 + bias; READ-ONCE K-staged LDS GEMM.

#define H 256
#define LSEQ 4096
#define NB 4
#define NMODES 32
#define T 64
#define NC 64   // LSEQ / T
#define NSEG 4
#define SEGC 16 // NC / NSEG

typedef _Float16 f16;
typedef _Float16 f16x2 __attribute__((ext_vector_type(2)));
typedef _Float16 f16x4 __attribute__((ext_vector_type(4)));
typedef _Float16 f16x8 __attribute__((ext_vector_type(8)));
typedef float f32x4 __attribute__((ext_vector_type(4)));
union U16x8 { f16x8 v; f16x2 h[4]; uint4 q; };
union U16x4 { f16x4 v; f16x2 h[2]; };

// cvt_pkrtz returns __fp16x2; bit-cast to _Float16x2
static __device__ __forceinline__ f16x2 pk(float a, float b) {
    typedef __fp16 fp16x2n __attribute__((ext_vector_type(2)));
    fp16x2n r = __builtin_amdgcn_cvt_pkrtz(a, b);
    return __builtin_bit_cast(f16x2, r);
}

__global__ __launch_bounds__(512) void k_setup(
    const float* __restrict__ log_dt, const float* __restrict__ w_re, const float* __restrict__ w_im,
    const float* __restrict__ B_re, const float* __restrict__ B_im,
    const float* __restrict__ C_re, const float* __restrict__ C_im,
    const float* __restrict__ W,
    float2* __restrict__ P, f16* __restrict__ Mh, f16* __restrict__ Wh,
    float2* __restrict__ dAT, float* __restrict__ dCB)
{
    __shared__ float ks_lds[T];
    __shared__ float ERe_lds[NMODES * T];
    __shared__ float EIm_lds[NMODES * T];

    int tid = threadIdx.x;
    int h = blockIdx.x;
    int n = tid & 31;
    int pg = tid >> 5;                 // 16 groups of 4 consecutive p
    int hn = h * NMODES + n;

    if (tid < 256) Wh[h * 256 + tid] = (f16)W[h * 256 + tid];

    double dt = exp((double)log_dt[h]);
    double zr = 0.5 * dt * (double)w_re[hn], zi = 0.5 * dt * (double)w_im[hn];
    double dr = 1.0 - zr, di = -zi;
    double dn = dr * dr + di * di;
    double nr = 1.0 + zr, ni = zi;
    double dAr = (nr * dr + ni * di) / dn, dAi = (ni * dr - nr * di) / dn;
    double tbr = dt * (double)B_re[hn], tbi = dt * (double)B_im[hn];
    double dBr = (tbr * dr + tbi * di) / dn, dBi = (tbi * dr - tbr * di) / dn;
    double Cr = (double)C_re[hn], Ci = (double)C_im[hn];
    double CBr = Cr * dBr - Ci * dBi, CBi = Cr * dBi + Ci * dBr;

    // jump-in: dA^(pg*4) via squarings (need dA^4,8,16,32)
    double d2r = dAr*dAr - dAi*dAi,  d2i = 2.0*dAr*dAi;
    double d4r = d2r*d2r - d2i*d2i,  d4i = 2.0*d2r*d2i;
    double d8r = d4r*d4r - d4i*d4i,  d8i = 2.0*d4r*d4i;
    double d16r= d8r*d8r - d8i*d8i,  d16i= 2.0*d8r*d8i;
    double d32r= d16r*d16r - d16i*d16i, d32i = 2.0*d16r*d16i;
    double ar = 1.0, ai = 0.0;
    if (pg & 1) { double t0 = ar*d4r - ai*d4i;  ai = ar*d4i + ai*d4r;  ar = t0; }
    if (pg & 2) { double t0 = ar*d8r - ai*d8i;  ai = ar*d8i + ai*d8r;  ar = t0; }
    if (pg & 4) { double t0 = ar*d16r - ai*d16i; ai = ar*d16i + ai*d16r; ar = t0; }
    if (pg & 8) { double t0 = ar*d32r - ai*d32i; ai = ar*d32i + ai*d32r; ar = t0; }

    #pragma unroll
    for (int i = 0; i < 4; ++i) {
        int p = pg * 4 + i;
        double pr = dBr * ar - dBi * ai, pi = dBr * ai + dBi * ar;
        P[(h * T + p) * NMODES + n] = make_float2((float)pr, (float)pi);
        float q = (float)(CBr * ar - CBi * ai);
        #pragma unroll
        for (int m = 16; m >= 1; m >>= 1) q += __shfl_xor(q, m);
        if (n == 0) ks_lds[p] = 2.0f * q;
        double nar = ar * dAr - ai * dAi;
        ai = ar * dAi + ai * dAr; ar = nar;
        ERe_lds[n * T + p] = (float)(2.0 * (Cr * ar - Ci * ai));
        EIm_lds[n * T + p] = (float)(2.0 * (Cr * ai + Ci * ar));
    }
    if (pg == 15) dAT[hn] = make_float2((float)ar, (float)ai);   // dA^64
    if (pg == 0) {
        float s1 = (float)dBr, s2 = (float)CBr;
        #pragma unroll
        for (int m = 16; m >= 1; m >>= 1) { s1 += __shfl_xor(s1, m); s2 += __shfl_xor(s2, m); }
        if (n == 0) dCB[h] = 4.0f * s1 * s2;
    }
    __syncthreads();

    // phase 2: Mh[t][k]: k<64: Toeplitz kshort[t-k]; 64..95: ERe[n][t]; 96..127: EIm[n][t]
    int t = tid >> 3, kq = tid & 7;    // 8 groups of 16 k
    U16x8 w4[2];
    #pragma unroll
    for (int i = 0; i < 16; ++i) {
        int k = kq * 16 + i;
        float val;
        if (k < 64)       val = (k <= t) ? ks_lds[t - k] : 0.f;
        else if (k < 96)  val = ERe_lds[(k - 64) * T + t];
        else              val = EIm_lds[(k - 96) * T + t];
        w4[i >> 3].h[(i >> 1) & 3][i & 1] = (f16)val;
    }
    uint4* dst = (uint4*)(Mh + ((size_t)(h * T) + t) * 128 + kq * 16);
    dst[0] = w4[0].q;
    dst[1] = w4[1].q;
}

// one block per (b,h): stage u in LDS; thread = (mode-pair n16, 4 chunks);
// P read as float4 per j (2 complex modes), quarter-wave broadcast.
__global__ __launch_bounds__(256) void k_local(
    const float* __restrict__ u, const float2* __restrict__ P,
    float* __restrict__ SLre, float* __restrict__ SLim)
{
    __shared__ float u_s[64 * 68];               // stride 68: 16B-aligned, 2-way banks
    int tid = threadIdx.x;
    int bh = blockIdx.x;
    int h = bh & (H - 1);

    const float4* uv4 = (const float4*)(u + (size_t)bh * LSEQ);
    #pragma unroll
    for (int it = 0; it < 4; ++it) {
        int f = tid + it * 256;                  // float4 index (1024 total)
        int c = f >> 4, j4 = (f & 15) * 4;
        *(float4*)(&u_s[c * 68 + j4]) = uv4[f];
    }
    __syncthreads();

    int n16 = tid & 15, cq = tid >> 4;           // chunks 4cq..4cq+3
    float2 acc[4][2];
    #pragma unroll
    for (int i = 0; i < 4; ++i) { acc[i][0] = make_float2(0.f,0.f); acc[i][1] = make_float2(0.f,0.f); }

    const float4* P4 = (const float4*)P;
    size_t prow = (size_t)h * T;
    #pragma unroll 4
    for (int j = 0; j < T; ++j) {
        float4 pv = P4[(prow + (T - 1 - j)) * 16 + n16];   // modes 2n16, 2n16+1
        #pragma unroll
        for (int i = 0; i < 4; ++i) {
            float uval = u_s[(cq * 4 + i) * 68 + j];
            acc[i][0].x += pv.x * uval; acc[i][0].y += pv.y * uval;
            acc[i][1].x += pv.z * uval; acc[i][1].y += pv.w * uval;
        }
    }
    #pragma unroll
    for (int i = 0; i < 4; ++i) {
        int c = cq * 4 + i;
        size_t idx = ((size_t)bh * NC + c) * NMODES + 2 * n16;
        *(float2*)(SLre + idx) = make_float2(acc[i][0].x, acc[i][1].x);
        *(float2*)(SLim + idx) = make_float2(acc[i][0].y, acc[i][1].y);
    }
}

// scan pass A: per (bh,n,seg): local scan of 16 chunks (slot <- local prefix,
// im NOT yet negated), carry = segment total.
__global__ __launch_bounds__(256) void k_scanA(
    const float2* __restrict__ dAT, float* __restrict__ SLre, float* __restrict__ SLim,
    float2* __restrict__ Carry)
{
    int gid = blockIdx.x * 256 + threadIdx.x;    // bh*128 + seg*32 + n
    int n = gid & 31;
    int seg = (gid >> 5) & 3;
    int bh = gid >> 7;
    int h = bh & (H - 1);
    float2 A = dAT[h * NMODES + n];
    float Sr = 0.f, Si = 0.f;
    size_t base = ((size_t)bh * NC + seg * SEGC) * NMODES + n;
    for (int r = 0; r < SEGC; ++r) {
        size_t idx = base + (size_t)r * NMODES;
        float lr = SLre[idx], li = SLim[idx];
        SLre[idx] = Sr; SLim[idx] = Si;
        float ns = Sr * A.x - Si * A.y + lr;
        Si = Sr * A.y + Si * A.x + li;
        Sr = ns;
    }
    Carry[((size_t)bh * NSEG + seg) * NMODES + n] = make_float2(Sr, Si);
}

// scan pass B: E_seg = Horner(carries, A16); slot <- E_seg*A^r + prefix (im negated).
__global__ __launch_bounds__(256) void k_scanB(
    const float2* __restrict__ dAT, float* __restrict__ SLre, float* __restrict__ SLim,
    const float2* __restrict__ Carry)
{
    int gid = blockIdx.x * 256 + threadIdx.x;
    int n = gid & 31;
    int seg = (gid >> 5) & 3;
    int bh = gid >> 7;
    int h = bh & (H - 1);
    float2 A = dAT[h * NMODES + n];
    // A16 = A^16 by 4 squarings
    float ar = A.x, ai = A.y;
    #pragma unroll
    for (int s = 0; s < 4; ++s) { float t = ar*ar - ai*ai; ai = 2.f*ar*ai; ar = t; }
    // E = sum_{j<seg} A16^(seg-1-j) * C_j  (Horner)
    float Er = 0.f, Ei = 0.f;
    const float2* Cb = Carry + (size_t)bh * NSEG * NMODES + n;
    for (int j = 0; j < seg; ++j) {
        float2 C = Cb[(size_t)j * NMODES];
        float t = Er * ar - Ei * ai + C.x;
        Ei = Er * ai + Ei * ar + C.y;
        Er = t;
    }
    float Vr = Er, Vi = Ei;
    size_t base = ((size_t)bh * NC + seg * SEGC) * NMODES + n;
    for (int r = 0; r < SEGC; ++r) {
        size_t idx = base + (size_t)r * NMODES;
        float lr = SLre[idx], li = SLim[idx];
        SLre[idx] = Vr + lr;
        SLim[idx] = -(Vi + li);
        float t = Vr * A.x - Vi * A.y;
        Vi = Vr * A.y + Vi * A.x;
        Vr = t;
    }
}

// grid (H, 4): Y(64t x 64q) = Mh(64x128) x V(128x64), V = [u | Sre | -Sim].
// Wave w owns q-tile [qq*64 + w*16, +16) -> acc[4tt]; q-split for occupancy.
__global__ __launch_bounds__(256) void k_main(
    const float* __restrict__ u, const f16* __restrict__ Mh,
    const float* __restrict__ SLre, const float* __restrict__ SLim,
    const float* __restrict__ dCB, const float* __restrict__ D,
    f16* __restrict__ YG)
{
    int h = blockIdx.x;
    int qq = blockIdx.y;
    int tid = threadIdx.x;
    int w = tid >> 6, lane = tid & 63;
    int l15 = lane & 15, g = lane >> 4;

    int q = qq * 64 + w * 16 + l15;
    int b = q >> 6, c = q & 63;

    f32x4 acc[4];
    #pragma unroll
    for (int i = 0; i < 4; ++i) acc[i] = (f32x4)0.f;

    const f16* Mbase = Mh + (size_t)h * T * 128;

    #pragma unroll
    for (int s = 0; s < 4; ++s) {
        // A-frags: 4 t-tiles; lane: row t = tt*16 + l15, k = 32s + 8g + e
        f16x8 a4[4];
        #pragma unroll
        for (int tt = 0; tt < 4; ++tt)
            a4[tt] = *(const f16x8*)(Mbase + (tt * 16 + l15) * 128 + 32 * s + 8 * g);

        U16x8 bf;
        f32x4 lo, hi;
        if (s < 2) {
            int j0 = 32 * s + 8 * g;
            const float* up = u + ((size_t)(b * H + h)) * LSEQ + c * T + j0;
            lo = *(const f32x4*)up;
            hi = *(const f32x4*)(up + 4);
        } else {
            int n0 = 8 * g;
            const float* sp = (s == 2 ? SLre : SLim) +
                              ((size_t)(b * H + h) * NC + c) * NMODES + n0;
            lo = *(const f32x4*)sp;
            hi = *(const f32x4*)(sp + 4);
        }
        bf.h[0] = pk(lo.x, lo.y);
        bf.h[1] = pk(lo.z, lo.w);
        bf.h[2] = pk(hi.x, hi.y);
        bf.h[3] = pk(hi.z, hi.w);
        #pragma unroll
        for (int tt = 0; tt < 4; ++tt)
            acc[tt] = __builtin_amdgcn_mfma_f32_16x16x32_f16(a4[tt], bf.v, acc[tt], 0, 0, 0);
    }

    // epilogue: D-skip + liquid + gelu; row t = tt*16 + g*4 + r, col = q
    float Dh = D[h], dCBh = dCB[h];
    #pragma unroll
    for (int tt = 0; tt < 4; ++tt) {
        int l0 = c * T + tt * 16 + g * 4;
        const float* ub = u + ((size_t)(b * H + h)) * LSEQ;
        f32x4 uv = *(const f32x4*)(ub + l0);
        float up0 = (l0 == 0) ? 0.f : ub[l0 - 1];
        float ups[4] = {up0, uv.x, uv.y, uv.z};
        f32x4 out4;
        #pragma unroll
        for (int r = 0; r < 4; ++r) {
            float y = acc[tt][r] + Dh * uv[r] + dCBh * uv[r] * ups[r];
            float y3 = y * y * y;
            out4[r] = 0.5f * y * (1.f + tanhf(0.7978845608028654f * (y + 0.044715f * y3)));
        }
        U16x4 o16;
        o16.h[0] = pk(out4[0], out4[1]);
        o16.h[1] = pk(out4[2], out4[3]);
        *(f16x4*)(YG + ((size_t)(b * H + h)) * LSEQ + l0) = o16.v;
    }
}

// out(256o x 16384L) = Wh(256x256) x YG16 + bias; YG read ONCE.
// 512 blocks: each 256o x 32L; 4 waves, wave w: o-range [64w, 64w+64).
// K-loop 8 steps of 32 h staged to LDS [32L][40] f16 (16B rows, uniform quad-banks).
#define KO_STRIDE 40
__global__ __launch_bounds__(256) void k_out(
    const f16* __restrict__ YG, const f16* __restrict__ Wh,
    const float* __restrict__ bias, float* __restrict__ out)
{
    __shared__ f16 lds_b[32 * KO_STRIDE];
    int tid = threadIdx.x;
    int w = tid >> 6, lane = tid & 63;
    int l15 = lane & 15, g = lane >> 4;
    int Lb = blockIdx.x * 32;
    int b = Lb >> 12, lbase = Lb & 4095;
    int o0 = w * 64;

    int hh = tid >> 3, l4 = (tid & 7) * 4;       // stage mapping

    f32x4 acc[4][2];
    #pragma unroll
    for (int i = 0; i < 4; ++i) { acc[i][0] = (f32x4)0.f; acc[i][1] = (f32x4)0.f; }

    const f16* ygb = YG + ((size_t)(b * H + hh)) * LSEQ + lbase + l4;
    f16x4 v = *(const f16x4*)ygb;                // step 0 prefetch

    for (int k = 0; k < 8; ++k) {
        if (k) __syncthreads();                  // compute(k-1) done
        #pragma unroll
        for (int i = 0; i < 4; ++i) lds_b[(l4 + i) * KO_STRIDE + hh] = v[i];
        if (k < 7) v = *(const f16x4*)(ygb + (size_t)(k + 1) * 32 * LSEQ);
        __syncthreads();

        f16x8 bf[2];
        #pragma unroll
        for (int lt = 0; lt < 2; ++lt)
            bf[lt] = *(const f16x8*)(&lds_b[(lt * 16 + l15) * KO_STRIDE + 8 * g]);
        #pragma unroll
        for (int ot = 0; ot < 4; ++ot) {
            f16x8 a = *(const f16x8*)(Wh + (size_t)(o0 + ot * 16 + l15) * 256 + k * 32 + 8 * g);
            acc[ot][0] = __builtin_amdgcn_mfma_f32_16x16x32_f16(a, bf[0], acc[ot][0], 0, 0, 0);
            acc[ot][1] = __builtin_amdgcn_mfma_f32_16x16x32_f16(a, bf[1], acc[ot][1], 0, 0, 0);
        }
    }

    #pragma unroll
    for (int ot = 0; ot < 4; ++ot) {
        #pragma unroll
        for (int lt = 0; lt < 2; ++lt) {
            int l = lbase + lt * 16 + l15;
            #pragma unroll
            for (int r = 0; r < 4; ++r) {
                int o = o0 + ot * 16 + g * 4 + r;
                out[((size_t)(b * 256 + o)) * LSEQ + l] = acc[ot][lt][r] + bias[o];
            }
        }
    }
}

extern "C" void kernel_launch(void* const* d_in, const int* in_sizes, int n_in,
                              void* d_out, int out_size, void* d_ws, size_t ws_size,
                              hipStream_t stream) {
    const float* u      = (const float*)d_in[0];
    const float* log_dt = (const float*)d_in[1];
    const float* w_re   = (const float*)d_in[2];
    const float* w_im   = (const float*)d_in[3];
    const float* B_re   = (const float*)d_in[4];
    const float* B_im   = (const float*)d_in[5];
    const float* C_re   = (const float*)d_in[6];
    const float* C_im   = (const float*)d_in[7];
    const float* Dp     = (const float*)d_in[8];
    const float* Wp     = (const float*)d_in[9];
    const float* bias   = (const float*)d_in[10];
    float* out = (float*)d_out;
    float* ws = (float*)d_ws;

    // workspace (float offsets)
    float2* P    = (float2*)(ws);                 // [0, 1048576)  (dead after k_local)
    f16*    Mh   = (f16*)(ws + 1048576);          // [1048576, 2097152)
    f16*    Wh   = (f16*)(ws + 2097152);          // [2097152, 2129920)
    float2* dAT  = (float2*)(ws + 2129920);       // [2129920, 2146304)
    float*  dCB  = ws + 2146304;                  // [2146304, 2146560)
    float*  SLre = ws + 2146560;                  // [2146560, 4243712)
    float*  SLim = ws + 4243712;                  // [4243712, 6340864)
    f16*    YG16 = (f16*)(ws + 6340864);          // 4.2M f16 = 2.1M floats
    float2* Carry = (float2*)(ws);                // reuses P region (dead after k_local)

    k_setup<<<H, 512, 0, stream>>>(log_dt, w_re, w_im, B_re, B_im, C_re, C_im,
                                   Wp, P, Mh, Wh, dAT, dCB);
    k_local<<<NB * H, 256, 0, stream>>>(u, P, SLre, SLim);
    k_scanA<<<NB * H * NSEG * NMODES / 256, 256, 0, stream>>>(dAT, SLre, SLim, Carry);
    k_scanB<<<NB * H * NSEG * NMODES / 256, 256, 0, stream>>>(dAT, SLre, SLim, Carry);
    dim3 gm(H, 4);
    k_main<<<gm, 256, 0, stream>>>(u, Mh, SLre, SLim, dCB, Dp, YG16);
    k_out<<<NB * LSEQ / 32, 256, 0, stream>>>(YG16, Wh, bias, out);
}

// Round 11
// 136.023 us; speedup vs baseline: 3.1867x; 1.0756x over previous
//
#include <hip/hip_runtime.h>
#include <math.h>

// S4 liquid forward. B=4, H=256, L=4096, N2=32, C=1.
// Chunked state-space scan; per-h chunk compute and output linear are f16 MFMA
// GEMMs (fp32 accum); state-carrying local sums + scan stay fp32.
//   K1 setup : mode tables (double), 512 thr: Mh f16, P fp32, dA^T, dCB, W->f16.
//   K2 lscan : FUSED local+scan: per (b,h) block computes 64 chunk local sums
//              (LDS-staged u, float4 P), then完成 the whole 64-chunk scan
//              in-block (LDS totals + Horner carry, ratio A_T^4) -> one SL write.
//              Replaces k_local+k_scanA+k_scanB; saves ~160 MB SL round-trips.
//   K3 main  : grid (H,4): Y(64t x 64q) = Mh(64x128) x V MFMA -> YG f16.
//   K4 out   : out = Wh(256x256) x YG16 + bias; READ-ONCE K-staged LDS GEMM.

#define H 256
#define LSEQ 4096
#define NB 4
#define NMODES 32
#define T 64
#define NC 64   // LSEQ / T

typedef _Float16 f16;
typedef _Float16 f16x2 __attribute__((ext_vector_type(2)));
typedef _Float16 f16x4 __attribute__((ext_vector_type(4)));
typedef _Float16 f16x8 __attribute__((ext_vector_type(8)));
typedef float f32x4 __attribute__((ext_vector_type(4)));
union U16x8 { f16x8 v; f16x2 h[4]; uint4 q; };
union U16x4 { f16x4 v; f16x2 h[2]; };

// cvt_pkrtz returns __fp16x2; bit-cast to _Float16x2
static __device__ __forceinline__ f16x2 pk(float a, float b) {
    typedef __fp16 fp16x2n __attribute__((ext_vector_type(2)));
    fp16x2n r = __builtin_amdgcn_cvt_pkrtz(a, b);
    return __builtin_bit_cast(f16x2, r);
}

static __device__ __forceinline__ float2 cmul(float2 a, float2 b) {
    return make_float2(a.x * b.x - a.y * b.y, a.x * b.y + a.y * b.x);
}

__global__ __launch_bounds__(512) void k_setup(
    const float* __restrict__ log_dt, const float* __restrict__ w_re, const float* __restrict__ w_im,
    const float* __restrict__ B_re, const float* __restrict__ B_im,
    const float* __restrict__ C_re, const float* __restrict__ C_im,
    const float* __restrict__ W,
    float2* __restrict__ P, f16* __restrict__ Mh, f16* __restrict__ Wh,
    float2* __restrict__ dAT, float* __restrict__ dCB)
{
    __shared__ float ks_lds[T];
    __shared__ float ERe_lds[NMODES * T];
    __shared__ float EIm_lds[NMODES * T];

    int tid = threadIdx.x;
    int h = blockIdx.x;
    int n = tid & 31;
    int pg = tid >> 5;                 // 16 groups of 4 consecutive p
    int hn = h * NMODES + n;

    if (tid < 256) Wh[h * 256 + tid] = (f16)W[h * 256 + tid];

    double dt = exp((double)log_dt[h]);
    double zr = 0.5 * dt * (double)w_re[hn], zi = 0.5 * dt * (double)w_im[hn];
    double dr = 1.0 - zr, di = -zi;
    double dn = dr * dr + di * di;
    double nr = 1.0 + zr, ni = zi;
    double dAr = (nr * dr + ni * di) / dn, dAi = (ni * dr - nr * di) / dn;
    double tbr = dt * (double)B_re[hn], tbi = dt * (double)B_im[hn];
    double dBr = (tbr * dr + tbi * di) / dn, dBi = (tbi * dr - tbr * di) / dn;
    double Cr = (double)C_re[hn], Ci = (double)C_im[hn];
    double CBr = Cr * dBr - Ci * dBi, CBi = Cr * dBi + Ci * dBr;

    // jump-in: dA^(pg*4) via squarings (need dA^4,8,16,32)
    double d2r = dAr*dAr - dAi*dAi,  d2i = 2.0*dAr*dAi;
    double d4r = d2r*d2r - d2i*d2i,  d4i = 2.0*d2r*d2i;
    double d8r = d4r*d4r - d4i*d4i,  d8i = 2.0*d4r*d4i;
    double d16r= d8r*d8r - d8i*d8i,  d16i= 2.0*d8r*d8i;
    double d32r= d16r*d16r - d16i*d16i, d32i = 2.0*d16r*d16i;
    double ar = 1.0, ai = 0.0;
    if (pg & 1) { double t0 = ar*d4r - ai*d4i;  ai = ar*d4i + ai*d4r;  ar = t0; }
    if (pg & 2) { double t0 = ar*d8r - ai*d8i;  ai = ar*d8i + ai*d8r;  ar = t0; }
    if (pg & 4) { double t0 = ar*d16r - ai*d16i; ai = ar*d16i + ai*d16r; ar = t0; }
    if (pg & 8) { double t0 = ar*d32r - ai*d32i; ai = ar*d32i + ai*d32r; ar = t0; }

    #pragma unroll
    for (int i = 0; i < 4; ++i) {
        int p = pg * 4 + i;
        double pr = dBr * ar - dBi * ai, pi = dBr * ai + dBi * ar;
        P[(h * T + p) * NMODES + n] = make_float2((float)pr, (float)pi);
        float q = (float)(CBr * ar - CBi * ai);
        #pragma unroll
        for (int m = 16; m >= 1; m >>= 1) q += __shfl_xor(q, m);
        if (n == 0) ks_lds[p] = 2.0f * q;
        double nar = ar * dAr - ai * dAi;
        ai = ar * dAi + ai * dAr; ar = nar;
        ERe_lds[n * T + p] = (float)(2.0 * (Cr * ar - Ci * ai));
        EIm_lds[n * T + p] = (float)(2.0 * (Cr * ai + Ci * ar));
    }
    if (pg == 15) dAT[hn] = make_float2((float)ar, (float)ai);   // dA^64
    if (pg == 0) {
        float s1 = (float)dBr, s2 = (float)CBr;
        #pragma unroll
        for (int m = 16; m >= 1; m >>= 1) { s1 += __shfl_xor(s1, m); s2 += __shfl_xor(s2, m); }
        if (n == 0) dCB[h] = 4.0f * s1 * s2;
    }
    __syncthreads();

    // phase 2: Mh[t][k]: k<64: Toeplitz kshort[t-k]; 64..95: ERe[n][t]; 96..127: EIm[n][t]
    int t = tid >> 3, kq = tid & 7;    // 8 groups of 16 k
    U16x8 w4[2];
    #pragma unroll
    for (int i = 0; i < 16; ++i) {
        int k = kq * 16 + i;
        float val;
        if (k < 64)       val = (k <= t) ? ks_lds[t - k] : 0.f;
        else if (k < 96)  val = ERe_lds[(k - 64) * T + t];
        else              val = EIm_lds[(k - 96) * T + t];
        w4[i >> 3].h[(i >> 1) & 3][i & 1] = (f16)val;
    }
    uint4* dst = (uint4*)(Mh + ((size_t)(h * T) + t) * 128 + kq * 16);
    dst[0] = w4[0].q;
    dst[1] = w4[1].q;
}

// FUSED local + full chunk-scan, one block per (b,h).
// Thread = (mode-pair n16 in 0..15, chunk-quad cq in 0..15; chunks 4cq..4cq+3).
// Phase 1: local sums (LDS-staged u, float4 P reads).
// Phase 2: quad total T = A^3 L0 + A^2 L1 + A L2 + L3 -> LDS.
// Phase 3: carry = Horner over preceding quads with ratio A^4.
// Phase 4: prefix walk; SL[c] <- state entering chunk c (im negated).
__global__ __launch_bounds__(256) void k_lscan(
    const float* __restrict__ u, const float2* __restrict__ P,
    const float2* __restrict__ dAT,
    float* __restrict__ SLre, float* __restrict__ SLim)
{
    __shared__ float u_s[64 * 68];               // stride 68: 16B-aligned, 2-way banks
    __shared__ float4 tot_lds[16][16];           // [cq][n16] = (re0,im0,re1,im1)
    int tid = threadIdx.x;
    int bh = blockIdx.x;
    int h = bh & (H - 1);

    const float4* uv4 = (const float4*)(u + (size_t)bh * LSEQ);
    #pragma unroll
    for (int it = 0; it < 4; ++it) {
        int f = tid + it * 256;                  // float4 index (1024 total)
        int c = f >> 4, j4 = (f & 15) * 4;
        *(float4*)(&u_s[c * 68 + j4]) = uv4[f];
    }
    __syncthreads();

    int n16 = tid & 15, cq = tid >> 4;           // chunks 4cq..4cq+3
    float2 acc[4][2];
    #pragma unroll
    for (int i = 0; i < 4; ++i) { acc[i][0] = make_float2(0.f,0.f); acc[i][1] = make_float2(0.f,0.f); }

    const float4* P4 = (const float4*)P;
    size_t prow = (size_t)h * T;
    #pragma unroll 4
    for (int j = 0; j < T; ++j) {
        float4 pv = P4[(prow + (T - 1 - j)) * 16 + n16];   // modes 2n16, 2n16+1
        #pragma unroll
        for (int i = 0; i < 4; ++i) {
            float uval = u_s[(cq * 4 + i) * 68 + j];
            acc[i][0].x += pv.x * uval; acc[i][0].y += pv.y * uval;
            acc[i][1].x += pv.z * uval; acc[i][1].y += pv.w * uval;
        }
    }

    // chunk-transfer ratio A = dA^64 per mode
    float2 A0 = dAT[h * NMODES + 2 * n16];
    float2 A1 = dAT[h * NMODES + 2 * n16 + 1];

    // quad total: T = A^3 L0 + A^2 L1 + A L2 + L3 (walk)
    float2 T0 = make_float2(0.f, 0.f), T1 = make_float2(0.f, 0.f);
    #pragma unroll
    for (int i = 0; i < 4; ++i) {
        T0 = cmul(A0, T0); T0.x += acc[i][0].x; T0.y += acc[i][0].y;
        T1 = cmul(A1, T1); T1.x += acc[i][1].x; T1.y += acc[i][1].y;
    }
    tot_lds[cq][n16] = make_float4(T0.x, T0.y, T1.x, T1.y);
    __syncthreads();

    // carry over preceding quads, ratio R = A^4 (Horner)
    float2 R0 = cmul(A0, A0); R0 = cmul(R0, R0);
    float2 R1 = cmul(A1, A1); R1 = cmul(R1, R1);
    float2 S0 = make_float2(0.f, 0.f), S1 = make_float2(0.f, 0.f);
    for (int j = 0; j < cq; ++j) {
        float4 t = tot_lds[j][n16];
        S0 = cmul(R0, S0); S0.x += t.x; S0.y += t.y;
        S1 = cmul(R1, S1); S1.x += t.z; S1.y += t.w;
    }

    // prefix walk: slot c <- state entering chunk c (im negated)
    #pragma unroll
    for (int i = 0; i < 4; ++i) {
        int c = cq * 4 + i;
        size_t idx = ((size_t)bh * NC + c) * NMODES + 2 * n16;
        *(float2*)(SLre + idx) = make_float2(S0.x, S1.x);
        *(float2*)(SLim + idx) = make_float2(-S0.y, -S1.y);
        S0 = cmul(A0, S0); S0.x += acc[i][0].x; S0.y += acc[i][0].y;
        S1 = cmul(A1, S1); S1.x += acc[i][1].x; S1.y += acc[i][1].y;
    }
}

// grid (H, 4): Y(64t x 64q) = Mh(64x128) x V(128x64), V = [u | Sre | -Sim].
// Wave w owns q-tile [qq*64 + w*16, +16) -> acc[4tt]; q-split for occupancy.
__global__ __launch_bounds__(256) void k_main(
    const float* __restrict__ u, const f16* __restrict__ Mh,
    const float* __restrict__ SLre, const float* __restrict__ SLim,
    const float* __restrict__ dCB, const float* __restrict__ D,
    f16* __restrict__ YG)
{
    int h = blockIdx.x;
    int qq = blockIdx.y;
    int tid = threadIdx.x;
    int w = tid >> 6, lane = tid & 63;
    int l15 = lane & 15, g = lane >> 4;

    int q = qq * 64 + w * 16 + l15;
    int b = q >> 6, c = q & 63;

    f32x4 acc[4];
    #pragma unroll
    for (int i = 0; i < 4; ++i) acc[i] = (f32x4)0.f;

    const f16* Mbase = Mh + (size_t)h * T * 128;

    #pragma unroll
    for (int s = 0; s < 4; ++s) {
        // A-frags: 4 t-tiles; lane: row t = tt*16 + l15, k = 32s + 8g + e
        f16x8 a4[4];
        #pragma unroll
        for (int tt = 0; tt < 4; ++tt)
            a4[tt] = *(const f16x8*)(Mbase + (tt * 16 + l15) * 128 + 32 * s + 8 * g);

        U16x8 bf;
        f32x4 lo, hi;
        if (s < 2) {
            int j0 = 32 * s + 8 * g;
            const float* up = u + ((size_t)(b * H + h)) * LSEQ + c * T + j0;
            lo = *(const f32x4*)up;
            hi = *(const f32x4*)(up + 4);
        } else {
            int n0 = 8 * g;
            const float* sp = (s == 2 ? SLre : SLim) +
                              ((size_t)(b * H + h) * NC + c) * NMODES + n0;
            lo = *(const f32x4*)sp;
            hi = *(const f32x4*)(sp + 4);
        }
        bf.h[0] = pk(lo.x, lo.y);
        bf.h[1] = pk(lo.z, lo.w);
        bf.h[2] = pk(hi.x, hi.y);
        bf.h[3] = pk(hi.z, hi.w);
        #pragma unroll
        for (int tt = 0; tt < 4; ++tt)
            acc[tt] = __builtin_amdgcn_mfma_f32_16x16x32_f16(a4[tt], bf.v, acc[tt], 0, 0, 0);
    }

    // epilogue: D-skip + liquid + gelu; row t = tt*16 + g*4 + r, col = q
    float Dh = D[h], dCBh = dCB[h];
    #pragma unroll
    for (int tt = 0; tt < 4; ++tt) {
        int l0 = c * T + tt * 16 + g * 4;
        const float* ub = u + ((size_t)(b * H + h)) * LSEQ;
        f32x4 uv = *(const f32x4*)(ub + l0);
        float up0 = (l0 == 0) ? 0.f : ub[l0 - 1];
        float ups[4] = {up0, uv.x, uv.y, uv.z};
        f32x4 out4;
        #pragma unroll
        for (int r = 0; r < 4; ++r) {
            float y = acc[tt][r] + Dh * uv[r] + dCBh * uv[r] * ups[r];
            float y3 = y * y * y;
            out4[r] = 0.5f * y * (1.f + tanhf(0.7978845608028654f * (y + 0.044715f * y3)));
        }
        U16x4 o16;
        o16.h[0] = pk(out4[0], out4[1]);
        o16.h[1] = pk(out4[2], out4[3]);
        *(f16x4*)(YG + ((size_t)(b * H + h)) * LSEQ + l0) = o16.v;
    }
}

// out(256o x 16384L) = Wh(256x256) x YG16 + bias; YG read ONCE.
// 512 blocks: each 256o x 32L; 4 waves, wave w: o-range [64w, 64w+64).
// K-loop 8 steps of 32 h staged to LDS [32L][40] f16 (16B rows, uniform quad-banks).
#define KO_STRIDE 40
__global__ __launch_bounds__(256) void k_out(
    const f16* __restrict__ YG, const f16* __restrict__ Wh,
    const float* __restrict__ bias, float* __restrict__ out)
{
    __shared__ f16 lds_b[32 * KO_STRIDE];
    int tid = threadIdx.x;
    int w = tid >> 6, lane = tid & 63;
    int l15 = lane & 15, g = lane >> 4;
    int Lb = blockIdx.x * 32;
    int b = Lb >> 12, lbase = Lb & 4095;
    int o0 = w * 64;

    int hh = tid >> 3, l4 = (tid & 7) * 4;       // stage mapping

    f32x4 acc[4][2];
    #pragma unroll
    for (int i = 0; i < 4; ++i) { acc[i][0] = (f32x4)0.f; acc[i][1] = (f32x4)0.f; }

    const f16* ygb = YG + ((size_t)(b * H + hh)) * LSEQ + lbase + l4;
    f16x4 v = *(const f16x4*)ygb;                // step 0 prefetch

    for (int k = 0; k < 8; ++k) {
        if (k) __syncthreads();                  // compute(k-1) done
        #pragma unroll
        for (int i = 0; i < 4; ++i) lds_b[(l4 + i) * KO_STRIDE + hh] = v[i];
        if (k < 7) v = *(const f16x4*)(ygb + (size_t)(k + 1) * 32 * LSEQ);
        __syncthreads();

        f16x8 bf[2];
        #pragma unroll
        for (int lt = 0; lt < 2; ++lt)
            bf[lt] = *(const f16x8*)(&lds_b[(lt * 16 + l15) * KO_STRIDE + 8 * g]);
        #pragma unroll
        for (int ot = 0; ot < 4; ++ot) {
            f16x8 a = *(const f16x8*)(Wh + (size_t)(o0 + ot * 16 + l15) * 256 + k * 32 + 8 * g);
            acc[ot][0] = __builtin_amdgcn_mfma_f32_16x16x32_f16(a, bf[0], acc[ot][0], 0, 0, 0);
            acc[ot][1] = __builtin_amdgcn_mfma_f32_16x16x32_f16(a, bf[1], acc[ot][1], 0, 0, 0);
        }
    }

    #pragma unroll
    for (int ot = 0; ot < 4; ++ot) {
        #pragma unroll
        for (int lt = 0; lt < 2; ++lt) {
            int l = lbase + lt * 16 + l15;
            #pragma unroll
            for (int r = 0; r < 4; ++r) {
                int o = o0 + ot * 16 + g * 4 + r;
                out[((size_t)(b * 256 + o)) * LSEQ + l] = acc[ot][lt][r] + bias[o];
            }
        }
    }
}

extern "C" void kernel_launch(void* const* d_in, const int* in_sizes, int n_in,
                              void* d_out, int out_size, void* d_ws, size_t ws_size,
                              hipStream_t stream) {
    const float* u      = (const float*)d_in[0];
    const float* log_dt = (const float*)d_in[1];
    const float* w_re   = (const float*)d_in[2];
    const float* w_im   = (const float*)d_in[3];
    const float* B_re   = (const float*)d_in[4];
    const float* B_im   = (const float*)d_in[5];
    const float* C_re   = (const float*)d_in[6];
    const float* C_im   = (const float*)d_in[7];
    const float* Dp     = (const float*)d_in[8];
    const float* Wp     = (const float*)d_in[9];
    const float* bias   = (const float*)d_in[10];
    float* out = (float*)d_out;
    float* ws = (float*)d_ws;

    // workspace (float offsets)
    float2* P    = (float2*)(ws);                 // [0, 1048576)  (dead after k_lscan)
    f16*    Mh   = (f16*)(ws + 1048576);          // [1048576, 2097152)
    f16*    Wh   = (f16*)(ws + 2097152);          // [2097152, 2129920)
    float2* dAT  = (float2*)(ws + 2129920);       // [2129920, 2146304)
    float*  dCB  = ws + 2146304;                  // [2146304, 2146560)
    float*  SLre = ws + 2146560;                  // [2146560, 4243712)
    float*  SLim = ws + 4243712;                  // [4243712, 6340864)
    f16*    YG16 = (f16*)(ws + 6340864);          // 4.2M f16 = 2.1M floats

    k_setup<<<H, 512, 0, stream>>>(log_dt, w_re, w_im, B_re, B_im, C_re, C_im,
                                   Wp, P, Mh, Wh, dAT, dCB);
    k_lscan<<<NB * H, 256, 0, stream>>>(u, P, dAT, SLre, SLim);
    dim3 gm(H, 4);
    k_main<<<gm, 256, 0, stream>>>(u, Mh, SLre, SLim, dCB, Dp, YG16);
    k_out<<<NB * LSEQ / 32, 256, 0, stream>>>(YG16, Wh, bias, out);
}

// Round 12
// 132.746 us; speedup vs baseline: 3.2654x; 1.0247x over previous
//
#include <hip/hip_runtime.h>
#include <math.h>

// S4 liquid forward. B=4, H=256, L=4096, N2=32, C=1.
// Chunked state-space scan; chunk compute + output linear are f16 MFMA GEMMs
// (fp32 accum); state-carrying math fp32 in-register.
//   K1 setup : ALL-FP32 mode tables (ref itself is fp32; DP was 4x-rate overkill):
//              Mh f16, P fp32, dA^T, dCB, W->f16.
//   K2 lscan : FUSED local+scan per (b,h): LDS u, float4 P, in-block 64-chunk
//              scan (quad totals + Horner carry, ratio A^4); SL stored f16 RTZ
//              (identical to k_main's old conversion, halves SL traffic).
//   K3 main  : grid (H,4): Y(64t x 64q) = Mh(64x128) x V MFMA -> YG f16.
//   K4 out   : out = Wh(256x256) x YG16 + bias; READ-ONCE K-staged LDS GEMM.

#define H 256
#define LSEQ 4096
#define NB 4
#define NMODES 32
#define T 64
#define NC 64   // LSEQ / T

typedef _Float16 f16;
typedef _Float16 f16x2 __attribute__((ext_vector_type(2)));
typedef _Float16 f16x4 __attribute__((ext_vector_type(4)));
typedef _Float16 f16x8 __attribute__((ext_vector_type(8)));
typedef float f32x4 __attribute__((ext_vector_type(4)));
union U16x8 { f16x8 v; f16x2 h[4]; uint4 q; };
union U16x4 { f16x4 v; f16x2 h[2]; };

// cvt_pkrtz returns __fp16x2; bit-cast to _Float16x2
static __device__ __forceinline__ f16x2 pk(float a, float b) {
    typedef __fp16 fp16x2n __attribute__((ext_vector_type(2)));
    fp16x2n r = __builtin_amdgcn_cvt_pkrtz(a, b);
    return __builtin_bit_cast(f16x2, r);
}

static __device__ __forceinline__ float2 cmul(float2 a, float2 b) {
    return make_float2(a.x * b.x - a.y * b.y, a.x * b.y + a.y * b.x);
}

__global__ __launch_bounds__(512) void k_setup(
    const float* __restrict__ log_dt, const float* __restrict__ w_re, const float* __restrict__ w_im,
    const float* __restrict__ B_re, const float* __restrict__ B_im,
    const float* __restrict__ C_re, const float* __restrict__ C_im,
    const float* __restrict__ W,
    float2* __restrict__ P, f16* __restrict__ Mh, f16* __restrict__ Wh,
    float2* __restrict__ dAT, float* __restrict__ dCB)
{
    __shared__ float ks_lds[T];
    __shared__ float ERe_lds[NMODES * T];
    __shared__ float EIm_lds[NMODES * T];

    int tid = threadIdx.x;
    int h = blockIdx.x;
    int n = tid & 31;
    int pg = tid >> 5;                 // 16 groups of 4 consecutive p
    int hn = h * NMODES + n;

    if (tid < 256) Wh[h * 256 + tid] = (f16)W[h * 256 + tid];

    float dt = expf(log_dt[h]);
    float zr = 0.5f * dt * w_re[hn], zi = 0.5f * dt * w_im[hn];
    float dr = 1.f - zr, di = -zi;
    float inv = 1.f / (dr * dr + di * di);
    float nr = 1.f + zr, ni = zi;
    float dAr = (nr * dr + ni * di) * inv, dAi = (ni * dr - nr * di) * inv;
    float tbr = dt * B_re[hn], tbi = dt * B_im[hn];
    float dBr = (tbr * dr + tbi * di) * inv, dBi = (tbi * dr - tbr * di) * inv;
    float Cr = C_re[hn], Ci = C_im[hn];
    float CBr = Cr * dBr - Ci * dBi, CBi = Cr * dBi + Ci * dBr;

    // jump-in: dA^(pg*4) via squarings (need dA^4,8,16,32)
    float d2r = dAr*dAr - dAi*dAi,  d2i = 2.f*dAr*dAi;
    float d4r = d2r*d2r - d2i*d2i,  d4i = 2.f*d2r*d2i;
    float d8r = d4r*d4r - d4i*d4i,  d8i = 2.f*d4r*d4i;
    float d16r= d8r*d8r - d8i*d8i,  d16i= 2.f*d8r*d8i;
    float d32r= d16r*d16r - d16i*d16i, d32i = 2.f*d16r*d16i;
    float ar = 1.f, ai = 0.f;
    if (pg & 1) { float t0 = ar*d4r - ai*d4i;  ai = ar*d4i + ai*d4r;  ar = t0; }
    if (pg & 2) { float t0 = ar*d8r - ai*d8i;  ai = ar*d8i + ai*d8r;  ar = t0; }
    if (pg & 4) { float t0 = ar*d16r - ai*d16i; ai = ar*d16i + ai*d16r; ar = t0; }
    if (pg & 8) { float t0 = ar*d32r - ai*d32i; ai = ar*d32i + ai*d32r; ar = t0; }

    #pragma unroll
    for (int i = 0; i < 4; ++i) {
        int p = pg * 4 + i;
        float pr = dBr * ar - dBi * ai, pi = dBr * ai + dBi * ar;
        P[(h * T + p) * NMODES + n] = make_float2(pr, pi);
        float q = CBr * ar - CBi * ai;
        #pragma unroll
        for (int m = 16; m >= 1; m >>= 1) q += __shfl_xor(q, m);
        if (n == 0) ks_lds[p] = 2.f * q;
        float nar = ar * dAr - ai * dAi;
        ai = ar * dAi + ai * dAr; ar = nar;
        ERe_lds[n * T + p] = 2.f * (Cr * ar - Ci * ai);
        EIm_lds[n * T + p] = 2.f * (Cr * ai + Ci * ar);
    }
    if (pg == 15) dAT[hn] = make_float2(ar, ai);   // dA^64
    if (pg == 0) {
        float s1 = dBr, s2 = CBr;
        #pragma unroll
        for (int m = 16; m >= 1; m >>= 1) { s1 += __shfl_xor(s1, m); s2 += __shfl_xor(s2, m); }
        if (n == 0) dCB[h] = 4.f * s1 * s2;
    }
    __syncthreads();

    // phase 2: Mh[t][k]: k<64: Toeplitz kshort[t-k]; 64..95: ERe[n][t]; 96..127: EIm[n][t]
    int t = tid >> 3, kq = tid & 7;    // 8 groups of 16 k
    U16x8 w4[2];
    #pragma unroll
    for (int i = 0; i < 16; ++i) {
        int k = kq * 16 + i;
        float val;
        if (k < 64)       val = (k <= t) ? ks_lds[t - k] : 0.f;
        else if (k < 96)  val = ERe_lds[(k - 64) * T + t];
        else              val = EIm_lds[(k - 96) * T + t];
        w4[i >> 3].h[(i >> 1) & 3][i & 1] = (f16)val;
    }
    uint4* dst = (uint4*)(Mh + ((size_t)(h * T) + t) * 128 + kq * 16);
    dst[0] = w4[0].q;
    dst[1] = w4[1].q;
}

// FUSED local + full chunk-scan, one block per (b,h).
// Thread = (mode-pair n16 in 0..15, chunk-quad cq in 0..15; chunks 4cq..4cq+3).
// SL written as f16 (RTZ pack == the conversion k_main used to apply).
__global__ __launch_bounds__(256) void k_lscan(
    const float* __restrict__ u, const float2* __restrict__ P,
    const float2* __restrict__ dAT,
    f16* __restrict__ SLre, f16* __restrict__ SLim)
{
    __shared__ float u_s[64 * 68];               // stride 68: 16B-aligned, 2-way banks
    __shared__ float4 tot_lds[16][16];           // [cq][n16] = (re0,im0,re1,im1)
    int tid = threadIdx.x;
    int bh = blockIdx.x;
    int h = bh & (H - 1);

    const float4* uv4 = (const float4*)(u + (size_t)bh * LSEQ);
    #pragma unroll
    for (int it = 0; it < 4; ++it) {
        int f = tid + it * 256;                  // float4 index (1024 total)
        int c = f >> 4, j4 = (f & 15) * 4;
        *(float4*)(&u_s[c * 68 + j4]) = uv4[f];
    }
    __syncthreads();

    int n16 = tid & 15, cq = tid >> 4;           // chunks 4cq..4cq+3
    float2 acc[4][2];
    #pragma unroll
    for (int i = 0; i < 4; ++i) { acc[i][0] = make_float2(0.f,0.f); acc[i][1] = make_float2(0.f,0.f); }

    const float4* P4 = (const float4*)P;
    size_t prow = (size_t)h * T;
    #pragma unroll 4
    for (int j = 0; j < T; ++j) {
        float4 pv = P4[(prow + (T - 1 - j)) * 16 + n16];   // modes 2n16, 2n16+1
        #pragma unroll
        for (int i = 0; i < 4; ++i) {
            float uval = u_s[(cq * 4 + i) * 68 + j];
            acc[i][0].x += pv.x * uval; acc[i][0].y += pv.y * uval;
            acc[i][1].x += pv.z * uval; acc[i][1].y += pv.w * uval;
        }
    }

    // chunk-transfer ratio A = dA^64 per mode
    float2 A0 = dAT[h * NMODES + 2 * n16];
    float2 A1 = dAT[h * NMODES + 2 * n16 + 1];

    // quad total: T = A^3 L0 + A^2 L1 + A L2 + L3 (walk)
    float2 T0 = make_float2(0.f, 0.f), T1 = make_float2(0.f, 0.f);
    #pragma unroll
    for (int i = 0; i < 4; ++i) {
        T0 = cmul(A0, T0); T0.x += acc[i][0].x; T0.y += acc[i][0].y;
        T1 = cmul(A1, T1); T1.x += acc[i][1].x; T1.y += acc[i][1].y;
    }
    tot_lds[cq][n16] = make_float4(T0.x, T0.y, T1.x, T1.y);
    __syncthreads();

    // carry over preceding quads, ratio R = A^4 (Horner)
    float2 R0 = cmul(A0, A0); R0 = cmul(R0, R0);
    float2 R1 = cmul(A1, A1); R1 = cmul(R1, R1);
    float2 S0 = make_float2(0.f, 0.f), S1 = make_float2(0.f, 0.f);
    for (int j = 0; j < cq; ++j) {
        float4 t = tot_lds[j][n16];
        S0 = cmul(R0, S0); S0.x += t.x; S0.y += t.y;
        S1 = cmul(R1, S1); S1.x += t.z; S1.y += t.w;
    }

    // prefix walk: slot c <- state entering chunk c (im negated), f16 RTZ
    #pragma unroll
    for (int i = 0; i < 4; ++i) {
        int c = cq * 4 + i;
        size_t idx = ((size_t)bh * NC + c) * NMODES + 2 * n16;
        *(f16x2*)(SLre + idx) = pk(S0.x, S1.x);
        *(f16x2*)(SLim + idx) = pk(-S0.y, -S1.y);
        S0 = cmul(A0, S0); S0.x += acc[i][0].x; S0.y += acc[i][0].y;
        S1 = cmul(A1, S1); S1.x += acc[i][1].x; S1.y += acc[i][1].y;
    }
}

// grid (H, 4): Y(64t x 64q) = Mh(64x128) x V(128x64), V = [u | Sre16 | Sim16].
// Wave w owns q-tile [qq*64 + w*16, +16) -> acc[4tt]; q-split for occupancy.
__global__ __launch_bounds__(256) void k_main(
    const float* __restrict__ u, const f16* __restrict__ Mh,
    const f16* __restrict__ SLre, const f16* __restrict__ SLim,
    const float* __restrict__ dCB, const float* __restrict__ D,
    f16* __restrict__ YG)
{
    int h = blockIdx.x;
    int qq = blockIdx.y;
    int tid = threadIdx.x;
    int w = tid >> 6, lane = tid & 63;
    int l15 = lane & 15, g = lane >> 4;

    int q = qq * 64 + w * 16 + l15;
    int b = q >> 6, c = q & 63;

    f32x4 acc[4];
    #pragma unroll
    for (int i = 0; i < 4; ++i) acc[i] = (f32x4)0.f;

    const f16* Mbase = Mh + (size_t)h * T * 128;

    #pragma unroll
    for (int s = 0; s < 4; ++s) {
        // A-frags: 4 t-tiles; lane: row t = tt*16 + l15, k = 32s + 8g + e
        f16x8 a4[4];
        #pragma unroll
        for (int tt = 0; tt < 4; ++tt)
            a4[tt] = *(const f16x8*)(Mbase + (tt * 16 + l15) * 128 + 32 * s + 8 * g);

        U16x8 bf;
        if (s < 2) {
            int j0 = 32 * s + 8 * g;
            const float* up = u + ((size_t)(b * H + h)) * LSEQ + c * T + j0;
            f32x4 lo = *(const f32x4*)up;
            f32x4 hi = *(const f32x4*)(up + 4);
            bf.h[0] = pk(lo.x, lo.y);
            bf.h[1] = pk(lo.z, lo.w);
            bf.h[2] = pk(hi.x, hi.y);
            bf.h[3] = pk(hi.z, hi.w);
        } else {
            int n0 = 8 * g;
            const f16* sp = (s == 2 ? SLre : SLim) +
                            ((size_t)(b * H + h) * NC + c) * NMODES + n0;
            bf.v = *(const f16x8*)sp;            // direct f16 load, no cvt
        }
        #pragma unroll
        for (int tt = 0; tt < 4; ++tt)
            acc[tt] = __builtin_amdgcn_mfma_f32_16x16x32_f16(a4[tt], bf.v, acc[tt], 0, 0, 0);
    }

    // epilogue: D-skip + liquid + gelu; row t = tt*16 + g*4 + r, col = q
    float Dh = D[h], dCBh = dCB[h];
    #pragma unroll
    for (int tt = 0; tt < 4; ++tt) {
        int l0 = c * T + tt * 16 + g * 4;
        const float* ub = u + ((size_t)(b * H + h)) * LSEQ;
        f32x4 uv = *(const f32x4*)(ub + l0);
        float up0 = (l0 == 0) ? 0.f : ub[l0 - 1];
        float ups[4] = {up0, uv.x, uv.y, uv.z};
        f32x4 out4;
        #pragma unroll
        for (int r = 0; r < 4; ++r) {
            float y = acc[tt][r] + Dh * uv[r] + dCBh * uv[r] * ups[r];
            float y3 = y * y * y;
            out4[r] = 0.5f * y * (1.f + tanhf(0.7978845608028654f * (y + 0.044715f * y3)));
        }
        U16x4 o16;
        o16.h[0] = pk(out4[0], out4[1]);
        o16.h[1] = pk(out4[2], out4[3]);
        *(f16x4*)(YG + ((size_t)(b * H + h)) * LSEQ + l0) = o16.v;
    }
}

// out(256o x 16384L) = Wh(256x256) x YG16 + bias; YG read ONCE.
// 512 blocks: each 256o x 32L; 4 waves, wave w: o-range [64w, 64w+64).
// K-loop 8 steps of 32 h staged to LDS [32L][40] f16 (16B rows, uniform quad-banks).
#define KO_STRIDE 40
__global__ __launch_bounds__(256) void k_out(
    const f16* __restrict__ YG, const f16* __restrict__ Wh,
    const float* __restrict__ bias, float* __restrict__ out)
{
    __shared__ f16 lds_b[32 * KO_STRIDE];
    int tid = threadIdx.x;
    int w = tid >> 6, lane = tid & 63;
    int l15 = lane & 15, g = lane >> 4;
    int Lb = blockIdx.x * 32;
    int b = Lb >> 12, lbase = Lb & 4095;
    int o0 = w * 64;

    int hh = tid >> 3, l4 = (tid & 7) * 4;       // stage mapping

    f32x4 acc[4][2];
    #pragma unroll
    for (int i = 0; i < 4; ++i) { acc[i][0] = (f32x4)0.f; acc[i][1] = (f32x4)0.f; }

    const f16* ygb = YG + ((size_t)(b * H + hh)) * LSEQ + lbase + l4;
    f16x4 v = *(const f16x4*)ygb;                // step 0 prefetch

    for (int k = 0; k < 8; ++k) {
        if (k) __syncthreads();                  // compute(k-1) done
        #pragma unroll
        for (int i = 0; i < 4; ++i) lds_b[(l4 + i) * KO_STRIDE + hh] = v[i];
        if (k < 7) v = *(const f16x4*)(ygb + (size_t)(k + 1) * 32 * LSEQ);
        __syncthreads();

        f16x8 bf[2];
        #pragma unroll
        for (int lt = 0; lt < 2; ++lt)
            bf[lt] = *(const f16x8*)(&lds_b[(lt * 16 + l15) * KO_STRIDE + 8 * g]);
        #pragma unroll
        for (int ot = 0; ot < 4; ++ot) {
            f16x8 a = *(const f16x8*)(Wh + (size_t)(o0 + ot * 16 + l15) * 256 + k * 32 + 8 * g);
            acc[ot][0] = __builtin_amdgcn_mfma_f32_16x16x32_f16(a, bf[0], acc[ot][0], 0, 0, 0);
            acc[ot][1] = __builtin_amdgcn_mfma_f32_16x16x32_f16(a, bf[1], acc[ot][1], 0, 0, 0);
        }
    }

    #pragma unroll
    for (int ot = 0; ot < 4; ++ot) {
        #pragma unroll
        for (int lt = 0; lt < 2; ++lt) {
            int l = lbase + lt * 16 + l15;
            #pragma unroll
            for (int r = 0; r < 4; ++r) {
                int o = o0 + ot * 16 + g * 4 + r;
                out[((size_t)(b * 256 + o)) * LSEQ + l] = acc[ot][lt][r] + bias[o];
            }
        }
    }
}

extern "C" void kernel_launch(void* const* d_in, const int* in_sizes, int n_in,
                              void* d_out, int out_size, void* d_ws, size_t ws_size,
                              hipStream_t stream) {
    const float* u      = (const float*)d_in[0];
    const float* log_dt = (const float*)d_in[1];
    const float* w_re   = (const float*)d_in[2];
    const float* w_im   = (const float*)d_in[3];
    const float* B_re   = (const float*)d_in[4];
    const float* B_im   = (const float*)d_in[5];
    const float* C_re   = (const float*)d_in[6];
    const float* C_im   = (const float*)d_in[7];
    const float* Dp     = (const float*)d_in[8];
    const float* Wp     = (const float*)d_in[9];
    const float* bias   = (const float*)d_in[10];
    float* out = (float*)d_out;
    float* ws = (float*)d_ws;

    // workspace (float offsets)
    float2* P      = (float2*)(ws);               // [0, 1048576)
    f16*    Mh     = (f16*)(ws + 1048576);        // [1048576, 2097152)
    f16*    Wh     = (f16*)(ws + 2097152);        // [2097152, 2129920)
    float2* dAT    = (float2*)(ws + 2129920);     // [2129920, 2146304)
    float*  dCB    = ws + 2146304;                // [2146304, 2146560)
    f16*    SLre16 = (f16*)(ws + 2146560);        // 2M f16 -> [2146560, 3195136)
    f16*    SLim16 = (f16*)(ws + 3195136);        // [3195136, 4243712)
    f16*    YG16   = (f16*)(ws + 4243712);        // [4243712, 5292288)

    k_setup<<<H, 512, 0, stream>>>(log_dt, w_re, w_im, B_re, B_im, C_re, C_im,
                                   Wp, P, Mh, Wh, dAT, dCB);
    k_lscan<<<NB * H, 256, 0, stream>>>(u, P, dAT, SLre16, SLim16);
    dim3 gm(H, 4);
    k_main<<<gm, 256, 0, stream>>>(u, Mh, SLre16, SLim16, dCB, Dp, YG16);
    k_out<<<NB * LSEQ / 32, 256, 0, stream>>>(YG16, Wh, bias, out);
}